// Round 11
// baseline (697.168 us; speedup 1.0000x reference)
//
#include <hip/hip_runtime.h>
#include <cstdint>
#include <cstddef>

#define NNODES 100000
#define NEDGES 1600000
// D = 128, C = 128 (hard-coded below)

typedef float f32x4 __attribute__((ext_vector_type(4)));
typedef unsigned int u32;
// native fp16 (no hip_fp16.h dependency — clang _Float16)
typedef _Float16 f16x2 __attribute__((ext_vector_type(2)));
typedef _Float16 f16x4 __attribute__((ext_vector_type(4)));
typedef _Float16 f16x8 __attribute__((ext_vector_type(8)));

// async global->LDS, 16B per lane: dest = lds_base + lane*16 (linear), src per-lane.
__device__ __forceinline__ void gload_lds16(const void* g, void* l) {
  __builtin_amdgcn_global_load_lds((const __attribute__((address_space(1))) u32*)g,
                                   (__attribute__((address_space(3))) u32*)l, 16, 0, 0);
}

// ---------------------------------------------------------------- utilities

__global__ void zero_int_kernel(int* __restrict__ p, int n) {
  int i = blockIdx.x * blockDim.x + threadIdx.x;
  if (i < n) p[i] = 0;
}

// int64 vs int32 edge_index detection (high words all zero => int64)
__global__ void detect_kernel(const unsigned int* __restrict__ ei, int* __restrict__ flag) {
  unsigned int v = ei[2 * threadIdx.x + 1];
  unsigned long long b = __ballot(v != 0u);
  if (threadIdx.x == 0) *flag = (b == 0ull) ? 1 : 0;
}

__device__ __forceinline__ int edge_val(const void* ei, int is64, long long idx) {
  if (is64) return (int)((const long long*)ei)[idx];
  return ((const int*)ei)[idx];
}

// ---------------------------------------------------------------- degree / CSR

__global__ void hist_kernel(const void* __restrict__ ei, const int* __restrict__ flag,
                            int* __restrict__ counts) {
  const int is64 = *flag;
  for (long long e = (long long)blockIdx.x * blockDim.x + threadIdx.x; e < NEDGES;
       e += (long long)gridDim.x * blockDim.x) {
    int d = edge_val(ei, is64, NEDGES + e);
    atomicAdd(&counts[d], 1);
  }
}

__global__ void dinv_kernel(const int* __restrict__ counts, float* __restrict__ dinv) {
  int i = blockIdx.x * blockDim.x + threadIdx.x;
  if (i < NNODES) dinv[i] = rsqrtf((float)(counts[i] + 1));  // +1 self loop
}

#define SCAN_B 256
#define SCAN_TILE 1024

__global__ void scan_reduce_kernel(const int* __restrict__ counts, int* __restrict__ bsums) {
  __shared__ int sd[SCAN_B];
  int t = threadIdx.x;
  int base = blockIdx.x * SCAN_TILE + t * 4;
  int s = 0;
#pragma unroll
  for (int i = 0; i < 4; i++) {
    int idx = base + i;
    if (idx < NNODES) s += counts[idx];
  }
  sd[t] = s;
  __syncthreads();
  for (int o = SCAN_B / 2; o > 0; o >>= 1) {
    if (t < o) sd[t] += sd[t + o];
    __syncthreads();
  }
  if (t == 0) bsums[blockIdx.x] = sd[0];
}

__global__ void scan_bsums_kernel(int* __restrict__ bsums, int* __restrict__ offs, int nb) {
  if (threadIdx.x == 0 && blockIdx.x == 0) {
    int run = 0;
    for (int b = 0; b < nb; b++) {
      int v = bsums[b];
      bsums[b] = run;
      run += v;
    }
    offs[NNODES] = run;
  }
}

__global__ void scan_write_kernel(const int* __restrict__ counts, const int* __restrict__ bsums,
                                  int* __restrict__ offs) {
  __shared__ int sd[SCAN_B];
  int t = threadIdx.x;
  int base = blockIdx.x * SCAN_TILE + t * 4;
  int v[4];
  int s = 0;
#pragma unroll
  for (int i = 0; i < 4; i++) {
    int idx = base + i;
    v[i] = (idx < NNODES) ? counts[idx] : 0;
    s += v[i];
  }
  sd[t] = s;
  __syncthreads();
  for (int o = 1; o < SCAN_B; o <<= 1) {
    int x = (t >= o) ? sd[t - o] : 0;
    __syncthreads();
    sd[t] += x;
    __syncthreads();
  }
  int run = sd[t] - s + bsums[blockIdx.x];
#pragma unroll
  for (int i = 0; i < 4; i++) {
    int idx = base + i;
    if (idx < NNODES) {
      offs[idx] = run;
      run += v[i];
    }
  }
}

// ---------------------------------------------------------------- bucketed CSR fill
// Pass A (bucket_kernel): partition edges into 391 dst-buckets of 256 nodes each.
// Pass B (fillwin_kernel): block b owns csr window [offs[b*256], offs[(b+1)*256));
//   scatter inside LDS, write back fully coalesced.
// Overflow fallbacks (never hit for Poisson(16) input) keep correctness unconditional.

#define BK_SHIFT 8
#define NBUCK 391   // ceil(NNODES / 256)
#define BCAP 8192   // pairs per bucket (mean 4096, +64 sigma)
#define WCAP 12288  // csr window ints in LDS (mean 4096, +128 sigma)

__global__ __launch_bounds__(256) void bucket_kernel(
    const void* __restrict__ ei, const int* __restrict__ flag, const int* __restrict__ offs,
    int* __restrict__ fillc, int* __restrict__ gcount,
    unsigned long long* __restrict__ bpairs, int* __restrict__ csr) {
  __shared__ int lcount[NBUCK];
  __shared__ int gbase[NBUCK];
  __shared__ int lcur[NBUCK];
  const int is64 = *flag;
  const int chunk = NEDGES / 256;  // 6250 (grid must be 256 blocks)
  const long long e0 = (long long)blockIdx.x * chunk;
  const long long e1 = e0 + chunk;
  for (int i = threadIdx.x; i < NBUCK; i += 256) {
    lcount[i] = 0;
    lcur[i] = 0;
  }
  __syncthreads();
  for (long long e = e0 + threadIdx.x; e < e1; e += 256) {
    int d = edge_val(ei, is64, NEDGES + e);
    atomicAdd(&lcount[d >> BK_SHIFT], 1);
  }
  __syncthreads();
  for (int i = threadIdx.x; i < NBUCK; i += 256) {
    int c = lcount[i];
    gbase[i] = c ? atomicAdd(&gcount[i], c) : 0;
  }
  __syncthreads();
  for (long long e = e0 + threadIdx.x; e < e1; e += 256) {
    int s = edge_val(ei, is64, e);
    int d = edge_val(ei, is64, NEDGES + e);
    int b = d >> BK_SHIFT;
    int pos = gbase[b] + atomicAdd(&lcur[b], 1);
    if (pos < BCAP) {
      bpairs[(size_t)b * BCAP + pos] =
          ((unsigned long long)(unsigned)d << 32) | (unsigned)s;
    } else {
      // bucket overflow: direct scatter (slow path, correctness only)
      int p = offs[d] + atomicAdd(&fillc[d], 1);
      csr[p] = s;
    }
  }
}

__global__ __launch_bounds__(256) void fillwin_kernel(
    const unsigned long long* __restrict__ bpairs, const int* __restrict__ gcount,
    const int* __restrict__ offs, int* __restrict__ fillc, int* __restrict__ csr) {
  __shared__ int win[WCAP];
  __shared__ int nfill[256];
  const int b = blockIdx.x;
  const int nlo = b << BK_SHIFT;
  const int nhi = min(nlo + 256, NNODES);
  const int base = offs[nlo];
  const int W = offs[nhi] - base;
  int cnt = gcount[b];
  if (cnt > BCAP) cnt = BCAP;
  if (W <= WCAP) {
    if ((int)threadIdx.x < nhi - nlo) nfill[threadIdx.x] = fillc[nlo + threadIdx.x];
    // preserve any fallback-written cells
    for (int i = threadIdx.x; i < W; i += 256) win[i] = csr[base + i];
    __syncthreads();
    for (int i = threadIdx.x; i < cnt; i += 256) {
      unsigned long long v = bpairs[(size_t)b * BCAP + i];
      int d = (int)(v >> 32);
      int s = (int)(v & 0xffffffffull);
      int p = offs[d] - base + atomicAdd(&nfill[d - nlo], 1);
      win[p] = s;
    }
    __syncthreads();
    for (int i = threadIdx.x; i < W; i += 256) csr[base + i] = win[i];
  } else {
    // window overflow: direct scatter (continues fillc from pass-A fallback)
    for (int i = threadIdx.x; i < cnt; i += 256) {
      unsigned long long v = bpairs[(size_t)b * BCAP + i];
      int d = (int)(v >> 32);
      int s = (int)(v & 0xffffffffull);
      int p = offs[d] + atomicAdd(&fillc[d], 1);
      csr[p] = s;
    }
  }
}

// ---------------------------------------------------------------- fp32 -> fp16 convert

__global__ void xcvt_kernel(const float* __restrict__ x, f16x4* __restrict__ y, int n4) {
  int i = blockIdx.x * blockDim.x + threadIdx.x;
  if (i >= n4) return;
  float4 v = ((const float4*)x)[i];
  f16x4 h;
  h[0] = (_Float16)v.x;
  h[1] = (_Float16)v.y;
  h[2] = (_Float16)v.z;
  h[3] = (_Float16)v.w;
  y[i] = h;
}

// ---------------------------------------------------------------- prescale (fp16 in/out)

__global__ void prescale16_kernel(const f16x4* __restrict__ x, const float* __restrict__ dinv,
                                  f16x4* __restrict__ y) {
  int i = blockIdx.x * blockDim.x + threadIdx.x;  // over NNODES*32 f16x4
  if (i >= NNODES * 32) return;
  int row = i >> 5;
  float s = dinv[row];
  f16x4 v = x[i];
  f16x4 h;
  h[0] = (_Float16)((float)v[0] * s);
  h[1] = (_Float16)((float)v[1] * s);
  h[2] = (_Float16)((float)v[2] * s);
  h[3] = (_Float16)((float)v[3] * s);
  y[i] = h;
}

// ---------------------------------------------------------------- aggregation (gather, fp16 in)
// 16B/lane gather restructure (r10: 4B/lane, 8 rows in flight, 3.24 TB/s eff,
// latency-bound). Wave = 4 x 16-lane groups; group g loads neighbor csr[p+4i+g]'s
// full 256B row as 16 x f16x8 (global_load_dwordx4). Main loop step 16 -> 4 load
// instrs, 16 rows in flight, 4x fewer memory instructions. fp32 accumulate (8
// channels/lane), one cross-group __shfl_xor(16/32) reduce per node, group 0
// writes the 256B output row coalesced.

__global__ __launch_bounds__(256) void aggregate_half_kernel(
    const _Float16* __restrict__ in, void* __restrict__ out, int out_half,
    const int* __restrict__ offs, const int* __restrict__ csr, const float* __restrict__ dinv,
    const float* __restrict__ bias) {
  int node = blockIdx.x * 4 + (threadIdx.x >> 6);
  if (node >= NNODES) return;
  const int lane = threadIdx.x & 63;
  const int g = lane >> 4;   // neighbor slot 0..3
  const int lg = lane & 15;  // 16B chunk within row (8 halfs)
  int beg = offs[node], end = offs[node + 1];

  float acc[8];
#pragma unroll
  for (int i = 0; i < 8; i++) acc[i] = 0.f;

  int p = beg;
  for (; p + 16 <= end; p += 16) {
    int j0 = csr[p + g];
    int j1 = csr[p + 4 + g];
    int j2 = csr[p + 8 + g];
    int j3 = csr[p + 12 + g];
    f16x8 h0 = *(const f16x8*)(in + (size_t)j0 * 128 + lg * 8);
    f16x8 h1 = *(const f16x8*)(in + (size_t)j1 * 128 + lg * 8);
    f16x8 h2 = *(const f16x8*)(in + (size_t)j2 * 128 + lg * 8);
    f16x8 h3 = *(const f16x8*)(in + (size_t)j3 * 128 + lg * 8);
#pragma unroll
    for (int i = 0; i < 8; i++) {
      acc[i] += ((float)h0[i] + (float)h1[i]) + ((float)h2[i] + (float)h3[i]);
    }
  }
  for (; p < end; p += 4) {
    int cnt = end - p;  // 1..4
    int jj = csr[p + (g < cnt ? g : 0)];
    f16x8 h = *(const f16x8*)(in + (size_t)jj * 128 + lg * 8);
    if (g < cnt) {
#pragma unroll
      for (int i = 0; i < 8; i++) acc[i] += (float)h[i];
    }
  }

  // cross-group reduce: sum the 4 group-partials (lanes differing in bits 4,5)
#pragma unroll
  for (int i = 0; i < 8; i++) {
    acc[i] += __shfl_xor(acc[i], 16);
    acc[i] += __shfl_xor(acc[i], 32);
  }

  // self term (pre-scaled row), then scale+bias
  f16x8 hs = *(const f16x8*)(in + (size_t)node * 128 + lg * 8);
  float di = dinv[node];
  if (g == 0) {
    int c = lg * 8;
    if (out_half) {
      f16x8 r;
#pragma unroll
      for (int i = 0; i < 8; i++) {
        float v = di * (acc[i] + (float)hs[i]);
        if (bias) v += bias[c + i];
        r[i] = (_Float16)v;
      }
      *(f16x8*)((_Float16*)out + (size_t)node * 128 + c) = r;
    } else {
      float r[8];
#pragma unroll
      for (int i = 0; i < 8; i++) {
        float v = di * (acc[i] + (float)hs[i]);
        if (bias) v += bias[c + i];
        r[i] = v;
      }
      float* op = (float*)out + (size_t)node * 128 + c;
      *(float4*)op = make_float4(r[0], r[1], r[2], r[3]);
      *(float4*)(op + 4) = make_float4(r[4], r[5], r[6], r[7]);
    }
  }
}

// ---------------------------------------------------------------- weight prep
// W [K][M] fp32  ->  Wt [M][K] fp16 (transposed).  Single fp16 — wl dropped:
// A is already fp16 (2^-11), wl only polished the smaller error source.

__global__ void wprep_f16_kernel(const float* __restrict__ W, int K, int M,
                                 _Float16* __restrict__ th) {
  int i = blockIdx.x * blockDim.x + threadIdx.x;
  if (i >= K * M) return;
  int k = i / M, m = i - k * M;
  th[(size_t)m * K + k] = (_Float16)W[i];
}

// ---------------------------------------------------------------- fp16 MFMA GEMM
// C[n,M] = concat(A0,A1,A2) @ W (+row_scale)(+bias)(+relu).  All fp16 operands,
// fp32 accumulate, 1 MFMA per tile per K-step.
// 2-PHASE DOUBLE-BUFFERED staging; LDS 32 KB (one smem block: As[2] | Bs[2]).
// EPILOGUE (out_half): LDS-staged coalesced writes (r9 PMC: direct 32B fp16 runs
// caused 2.15x sector amplification; staging removed it, r10 confirmed -62us).

#define BM 128
#define BN 128
#define BK 32

__global__ __launch_bounds__(256) void gemm_f16_kernel(
    const _Float16* __restrict__ A0, int K0, const _Float16* __restrict__ A1, int K1,
    const _Float16* __restrict__ A2, int K2, const _Float16* __restrict__ Bth, int Ktot, int M,
    const float* __restrict__ bias, const float* __restrict__ row_scale,
    void* __restrict__ Cmat, int relu, int out_half, int nrows) {
  __shared__ _Float16 smem[4 * BM * BK];  // 32 KB: As[2] | Bs[2]; reused as C-tile
  _Float16* const As0 = smem;
  _Float16* const Bs0 = smem + 2 * BM * BK;

  const int tid = threadIdx.x;
  const int lane = tid & 63;
  const int wv = tid >> 6;
  const int mBase = (wv >> 1) * 64;
  const int nBase = (wv & 1) * 64;
  const int ml = lane & 15;
  const int quad = lane >> 4;
  const int rowBase = blockIdx.x * BM;
  const int colBase = blockIdx.y * BN;

  // staging geometry: wave wv stages tile rows [wv*32, wv*32+32) of A and B.
  const int lrow = lane >> 2;  // 0..15
  const int lslot = lane & 3;  // 16B slot within 64B row

  f32x4 acc[4][4];
  const f32x4 zero = {0.f, 0.f, 0.f, 0.f};
#pragma unroll
  for (int i = 0; i < 4; i++)
#pragma unroll
    for (int j = 0; j < 4; j++) acc[i][j] = zero;

  auto stage = [&](int k0, int buf) {
    const _Float16* Ap;
    int kl, Kp;
    if (k0 < K0) {
      Ap = A0; kl = k0; Kp = K0;
    } else if (k0 < K0 + K1) {
      Ap = A1; kl = k0 - K0; Kp = K1;
    } else {
      Ap = A2; kl = k0 - K0 - K1; Kp = K2;
    }
    char* Ab = (char*)(As0 + buf * BM * BK);
    char* Bb = (char*)(Bs0 + buf * BN * BK);
#pragma unroll
    for (int c = 0; c < 2; c++) {
      int trow = wv * 32 + c * 16 + lrow;       // tile row 0..127
      int sws = lslot ^ (trow & 3);             // swizzled global 16B slot
      size_t ldsoff = (size_t)(wv * 32 + c * 16) * 64;  // bytes, wave-uniform
      int gr = rowBase + trow;
      if (gr > nrows - 1) gr = nrows - 1;       // clamp: garbage rows skipped on store
      gload_lds16(Ap + (size_t)gr * Kp + kl + sws * 8, Ab + ldsoff);
      gload_lds16(Bth + (size_t)(colBase + trow) * Ktot + k0 + sws * 8, Bb + ldsoff);
    }
  };

  const int ntile = Ktot / BK;
  stage(0, 0);
  __syncthreads();
  int cur = 0;
  for (int t = 0; t < ntile; ++t) {
    if (t + 1 < ntile) stage((t + 1) * BK, cur ^ 1);

    f16x8 av[4], bv[4];
#pragma unroll
    for (int nt = 0; nt < 4; nt++) {
      int nrow = nBase + nt * 16 + ml;
      int boff = nrow * 32 + ((quad ^ (nrow & 3)) << 3);
      bv[nt] = *(const f16x8*)&Bs0[cur * BN * BK + boff];
    }
#pragma unroll
    for (int mt = 0; mt < 4; mt++) {
      int mrow = mBase + mt * 16 + ml;
      int aoff = mrow * 32 + ((quad ^ (mrow & 3)) << 3);
      av[mt] = *(const f16x8*)&As0[cur * BM * BK + aoff];
    }
#pragma unroll
    for (int mt = 0; mt < 4; mt++)
#pragma unroll
      for (int nt = 0; nt < 4; nt++) {
        acc[mt][nt] =
            __builtin_amdgcn_mfma_f32_16x16x32_f16(av[mt], bv[nt], acc[mt][nt], 0, 0, 0);
      }
    __syncthreads();
    cur ^= 1;
  }

  // epilogue: C/D layout col=lane&15, row=quad*4+reg
  if (out_half) {
    // stage full 128x128 fp16 tile in smem (staging bufs dead past final barrier)
    _Float16* Ct = smem;
#pragma unroll
    for (int nt = 0; nt < 4; nt++) {
      int colL = nBase + nt * 16 + ml;
      float bv = bias ? bias[colBase + colL] : 0.f;
#pragma unroll
      for (int mt = 0; mt < 4; mt++) {
        int rowL0 = mBase + mt * 16 + quad * 4;
#pragma unroll
        for (int r = 0; r < 4; r++) {
          int rowL = rowL0 + r;
          int grow = rowBase + rowL;
          float v = acc[mt][nt][r];
          if (row_scale) v *= row_scale[grow < nrows ? grow : nrows - 1];
          v += bv;
          if (relu) v = fmaxf(v, 0.f);
          Ct[rowL * 128 + colL] = (_Float16)v;
        }
      }
    }
    __syncthreads();
    // coalesced copy-out: 128 rows x 256B = 2048 x 16B chunks
    for (int idx = tid; idx < 2048; idx += 256) {
      int rowL = idx >> 4;
      int chunk = idx & 15;
      int grow = rowBase + rowL;
      if (grow < nrows) {
        *(uint4*)((_Float16*)Cmat + (size_t)grow * M + colBase + chunk * 8) =
            *(const uint4*)&Ct[rowL * 128 + chunk * 8];
      }
    }
  } else {
#pragma unroll
    for (int nt = 0; nt < 4; nt++) {
      int col = colBase + nBase + nt * 16 + ml;
      float bv = bias ? bias[col] : 0.f;
#pragma unroll
      for (int mt = 0; mt < 4; mt++) {
        int row0 = rowBase + mBase + mt * 16 + quad * 4;
#pragma unroll
        for (int r = 0; r < 4; r++) {
          int grow = row0 + r;
          if (grow >= nrows) continue;
          float v = acc[mt][nt][r];
          if (row_scale) v *= row_scale[grow];
          v += bv;
          if (relu) v = fmaxf(v, 0.f);
          ((float*)Cmat)[(size_t)grow * M + col] = v;
        }
      }
    }
  }
}

// ---------------------------------------------------------------- launch

extern "C" void kernel_launch(void* const* d_in, const int* in_sizes, int n_in, void* d_out,
                              int out_size, void* d_ws, size_t ws_size, hipStream_t stream) {
  const float* x_self     = (const float*)d_in[0];
  const float* x_neighbor = (const float*)d_in[1];
  const void*  edge_index = d_in[2];
  const float* W_in_self  = (const float*)d_in[3];
  const float* b_in_self  = (const float*)d_in[4];
  const float* W_out_self = (const float*)d_in[5];
  const float* b_out_self = (const float*)d_in[6];
  const float* Wg1        = (const float*)d_in[7];
  const float* bg1        = (const float*)d_in[8];
  const float* Wg2        = (const float*)d_in[9];
  const float* bg2        = (const float*)d_in[10];
  const float* W_out      = (const float*)d_in[11];
  const float* b_out      = (const float*)d_in[12];
  float* out = (float*)d_out;

  char* ws = (char*)d_ws;
  size_t off = 0;
  auto alloc = [&](size_t bytes) -> void* {
    void* p = ws + off;
    off = (off + bytes + 255) & ~(size_t)255;
    return p;
  };
  int* counts = (int*)alloc((size_t)2 * NNODES * 4 + 2048);  // counts + fillc + gcount
  int* fillc  = counts + NNODES;
  int* gcount = counts + 2 * NNODES;                         // NBUCK ints
  int*   offs   = (int*)alloc((size_t)(NNODES + 1) * 4);
  int*   csr    = (int*)alloc((size_t)NEDGES * 4);
  int*   bsums  = (int*)alloc(4096);
  int*   flag   = (int*)alloc(256);
  float* dinv   = (float*)alloc((size_t)NNODES * 4);
  _Float16* wt1 = (_Float16*)alloc(32768 * 2);  // W_in_self  K=128 M=256
  _Float16* wt2 = (_Float16*)alloc(49152 * 2);  // W_out_self K=384 M=128
  _Float16* wt3 = (_Float16*)alloc(32768 * 2);  // Wg1        K=128 M=256
  _Float16* wt4 = (_Float16*)alloc(32768 * 2);  // Wg2        K=256 M=128
  _Float16* wt5 = (_Float16*)alloc(65536 * 2);  // W_out      K=512 M=128
  float* bufA = (float*)alloc((size_t)NNODES * 256 * 4);
  float* bufB = (float*)alloc((size_t)NNODES * 256 * 4);
  (void)ws_size;

  // bpairs (25.6 MB) aliases bufA: dead before GEMM-1 writes l1 there.
  unsigned long long* bpairs = (unsigned long long*)bufA;

  const int nb = (NNODES + SCAN_TILE - 1) / SCAN_TILE;  // 98
  const int gridRows = (NNODES + BM - 1) / BM;          // 782

  detect_kernel<<<1, 64, 0, stream>>>((const unsigned int*)edge_index, flag);
  zero_int_kernel<<<(2 * NNODES + 512 + 255) / 256, 256, 0, stream>>>(counts,
                                                                      2 * NNODES + 512);
  hist_kernel<<<1024, 256, 0, stream>>>(edge_index, flag, counts);
  dinv_kernel<<<(NNODES + 255) / 256, 256, 0, stream>>>(counts, dinv);
  scan_reduce_kernel<<<nb, SCAN_B, 0, stream>>>(counts, bsums);
  scan_bsums_kernel<<<1, 64, 0, stream>>>(bsums, offs, nb);
  scan_write_kernel<<<nb, SCAN_B, 0, stream>>>(counts, bsums, offs);
  bucket_kernel<<<256, 256, 0, stream>>>(edge_index, flag, offs, fillc, gcount, bpairs, csr);
  fillwin_kernel<<<NBUCK, 256, 0, stream>>>(bpairs, gcount, offs, fillc, csr);

  wprep_f16_kernel<<<(32768 + 255) / 256, 256, 0, stream>>>(W_in_self, 128, 256, wt1);
  wprep_f16_kernel<<<(49152 + 255) / 256, 256, 0, stream>>>(W_out_self, 384, 128, wt2);
  wprep_f16_kernel<<<(32768 + 255) / 256, 256, 0, stream>>>(Wg1, 128, 256, wt3);
  wprep_f16_kernel<<<(32768 + 255) / 256, 256, 0, stream>>>(Wg2, 256, 128, wt4);
  wprep_f16_kernel<<<(65536 + 255) / 256, 256, 0, stream>>>(W_out, 512, 128, wt5);

  // ---- fp16 copies of the fp32 inputs (in bufB's permanently-free top half) ----
  _Float16* xs16 = (_Float16*)(bufB + (size_t)NNODES * 128);
  _Float16* xn16 = xs16 + (size_t)NNODES * 128;
  xcvt_kernel<<<(NNODES * 32 + 255) / 256, 256, 0, stream>>>(x_self, (f16x4*)xs16, NNODES * 32);
  xcvt_kernel<<<(NNODES * 32 + 255) / 256, 256, 0, stream>>>(x_neighbor, (f16x4*)xn16,
                                                             NNODES * 32);

  // ---- dense self branch ----
  // l1 = relu(xs16 @ W1 + b1) stored fp16 [N,256] in bufA (bpairs dead by now)
  _Float16* l1 = (_Float16*)bufA;
  gemm_f16_kernel<<<dim3(gridRows, 2), 256, 0, stream>>>(
      xs16, 128, nullptr, 0, nullptr, 0, wt1, 128, 256, b_in_self, nullptr, l1, 1, 1, NNODES);
  gemm_f16_kernel<<<dim3(gridRows, 1), 256, 0, stream>>>(
      xs16, 128, l1, 256, nullptr, 0, wt2, 384, 128, b_out_self, nullptr, out, 0, 0, NNODES);

  // ---- GCN branch (A_norm @ (X W) == (A_norm @ X) W), all intermediates fp16 ----
  _Float16* ybuf = (_Float16*)bufB;
  _Float16* aggx = (_Float16*)bufA;
  _Float16* g1   = (_Float16*)bufB;
  _Float16* xw2  = (_Float16*)bufA;
  _Float16* g2   = (_Float16*)bufA + (size_t)NNODES * 128;

  prescale16_kernel<<<(NNODES * 32 + 255) / 256, 256, 0, stream>>>((const f16x4*)xn16, dinv,
                                                                   (f16x4*)ybuf);
  aggregate_half_kernel<<<NNODES / 4, 256, 0, stream>>>(ybuf, aggx, 1, offs, csr, dinv,
                                                        nullptr);
  gemm_f16_kernel<<<dim3(gridRows, 2), 256, 0, stream>>>(
      aggx, 128, nullptr, 0, nullptr, 0, wt3, 128, 256, bg1, nullptr, g1, 0, 1, NNODES);
  // xw2 = (fp16)((g1 @ Wg2) * dinv[row])  (pre-scale for agg2 folded into epilogue)
  gemm_f16_kernel<<<dim3(gridRows, 1), 256, 0, stream>>>(
      g1, 256, nullptr, 0, nullptr, 0, wt4, 256, 128, nullptr, dinv, xw2, 0, 1, NNODES);
  aggregate_half_kernel<<<NNODES / 4, 256, 0, stream>>>(xw2, g2, 1, offs, csr, dinv, bg2);
  gemm_f16_kernel<<<dim3(gridRows, 1), 256, 0, stream>>>(
      xn16, 128, g1, 256, g2, 128, wt5, 512, 128, b_out, nullptr,
      out + (size_t)NNODES * 128, 0, 0, NNODES);
}

// Round 12
// 660.338 us; speedup vs baseline: 1.0558x; 1.0558x over previous
//
#include <hip/hip_runtime.h>
#include <cstdint>
#include <cstddef>

#define NNODES 100000
#define NEDGES 1600000
// D = 128, C = 128 (hard-coded below)

typedef float f32x4 __attribute__((ext_vector_type(4)));
typedef unsigned int u32;
// native fp16 (no hip_fp16.h dependency — clang _Float16)
typedef _Float16 f16x2 __attribute__((ext_vector_type(2)));
typedef _Float16 f16x4 __attribute__((ext_vector_type(4)));
typedef _Float16 f16x8 __attribute__((ext_vector_type(8)));

// async global->LDS, 16B per lane: dest = lds_base + lane*16 (linear), src per-lane.
__device__ __forceinline__ void gload_lds16(const void* g, void* l) {
  __builtin_amdgcn_global_load_lds((const __attribute__((address_space(1))) u32*)g,
                                   (__attribute__((address_space(3))) u32*)l, 16, 0, 0);
}

// ---------------------------------------------------------------- utilities

__global__ void zero_int_kernel(int* __restrict__ p, int n) {
  int i = blockIdx.x * blockDim.x + threadIdx.x;
  if (i < n) p[i] = 0;
}

// int64 vs int32 edge_index detection (high words all zero => int64)
__global__ void detect_kernel(const unsigned int* __restrict__ ei, int* __restrict__ flag) {
  unsigned int v = ei[2 * threadIdx.x + 1];
  unsigned long long b = __ballot(v != 0u);
  if (threadIdx.x == 0) *flag = (b == 0ull) ? 1 : 0;
}

__device__ __forceinline__ int edge_val(const void* ei, int is64, long long idx) {
  if (is64) return (int)((const long long*)ei)[idx];
  return ((const int*)ei)[idx];
}

// ---------------------------------------------------------------- degree

__global__ void dinv_kernel(const int* __restrict__ counts, float* __restrict__ dinv) {
  int i = blockIdx.x * blockDim.x + threadIdx.x;
  if (i < NNODES) dinv[i] = rsqrtf((float)(counts[i] + 1));  // +1 self loop
}

#define SCAN_B 256
#define SCAN_TILE 1024

__global__ void scan_reduce_kernel(const int* __restrict__ counts, int* __restrict__ bsums) {
  __shared__ int sd[SCAN_B];
  int t = threadIdx.x;
  int base = blockIdx.x * SCAN_TILE + t * 4;
  int s = 0;
#pragma unroll
  for (int i = 0; i < 4; i++) {
    int idx = base + i;
    if (idx < NNODES) s += counts[idx];
  }
  sd[t] = s;
  __syncthreads();
  for (int o = SCAN_B / 2; o > 0; o >>= 1) {
    if (t < o) sd[t] += sd[t + o];
    __syncthreads();
  }
  if (t == 0) bsums[blockIdx.x] = sd[0];
}

__global__ void scan_bsums_kernel(int* __restrict__ bsums, int* __restrict__ offs, int nb) {
  if (threadIdx.x == 0 && blockIdx.x == 0) {
    int run = 0;
    for (int b = 0; b < nb; b++) {
      int v = bsums[b];
      bsums[b] = run;
      run += v;
    }
    offs[NNODES] = run;
  }
}

__global__ void scan_write_kernel(const int* __restrict__ counts, const int* __restrict__ bsums,
                                  int* __restrict__ offs) {
  __shared__ int sd[SCAN_B];
  int t = threadIdx.x;
  int base = blockIdx.x * SCAN_TILE + t * 4;
  int v[4];
  int s = 0;
#pragma unroll
  for (int i = 0; i < 4; i++) {
    int idx = base + i;
    v[i] = (idx < NNODES) ? counts[idx] : 0;
    s += v[i];
  }
  sd[t] = s;
  __syncthreads();
  for (int o = 1; o < SCAN_B; o <<= 1) {
    int x = (t >= o) ? sd[t - o] : 0;
    __syncthreads();
    sd[t] += x;
    __syncthreads();
  }
  int run = sd[t] - s + bsums[blockIdx.x];
#pragma unroll
  for (int i = 0; i < 4; i++) {
    int idx = base + i;
    if (idx < NNODES) {
      offs[idx] = run;
      run += v[i];
    }
  }
}

// ---------------------------------------------------------------- bucketed CSR fill
// Pass A (bucket_kernel): partition edges into 391 dst-buckets of 256 nodes each,
//   AND histogram global degree counts (hist_kernel folded in — bucket already
//   reads every dst). Bucket overflow pairs go to the ovf list (drained after the
//   scan produces offs); capacity = NEDGES so correctness is unconditional.
// Pass B (fillwin_kernel): block b owns csr window [offs[b*256], offs[(b+1)*256));
//   scatter inside LDS, write back fully coalesced.

#define BK_SHIFT 8
#define NBUCK 391   // ceil(NNODES / 256)
#define BCAP 8192   // pairs per bucket (mean 4096, +64 sigma)
#define WCAP 12288  // csr window ints in LDS (mean 4096, +128 sigma)

__global__ __launch_bounds__(256) void bucket_kernel(
    const void* __restrict__ ei, const int* __restrict__ flag, int* __restrict__ counts,
    int* __restrict__ gcount, unsigned long long* __restrict__ bpairs,
    unsigned long long* __restrict__ ovf, int* __restrict__ novf) {
  __shared__ int lcount[NBUCK];
  __shared__ int gbase[NBUCK];
  __shared__ int lcur[NBUCK];
  const int is64 = *flag;
  const int chunk = NEDGES / 256;  // 6250 (grid must be 256 blocks)
  const long long e0 = (long long)blockIdx.x * chunk;
  const long long e1 = e0 + chunk;
  for (int i = threadIdx.x; i < NBUCK; i += 256) {
    lcount[i] = 0;
    lcur[i] = 0;
  }
  __syncthreads();
  for (long long e = e0 + threadIdx.x; e < e1; e += 256) {
    int d = edge_val(ei, is64, NEDGES + e);
    atomicAdd(&lcount[d >> BK_SHIFT], 1);
    atomicAdd(&counts[d], 1);  // global degree histogram (was hist_kernel)
  }
  __syncthreads();
  for (int i = threadIdx.x; i < NBUCK; i += 256) {
    int c = lcount[i];
    gbase[i] = c ? atomicAdd(&gcount[i], c) : 0;
  }
  __syncthreads();
  for (long long e = e0 + threadIdx.x; e < e1; e += 256) {
    int s = edge_val(ei, is64, e);
    int d = edge_val(ei, is64, NEDGES + e);
    int b = d >> BK_SHIFT;
    int pos = gbase[b] + atomicAdd(&lcur[b], 1);
    unsigned long long pair = ((unsigned long long)(unsigned)d << 32) | (unsigned)s;
    if (pos < BCAP) {
      bpairs[(size_t)b * BCAP + pos] = pair;
    } else {
      // bucket overflow: append to ovf list (capacity NEDGES — always fits)
      int o = atomicAdd(novf, 1);
      ovf[o] = pair;
    }
  }
}

// drain overflow pairs (novf == 0 for Poisson(16) input — exits immediately)
__global__ void ovf_scatter_kernel(const unsigned long long* __restrict__ ovf,
                                   const int* __restrict__ novf, const int* __restrict__ offs,
                                   int* __restrict__ fillc, int* __restrict__ csr) {
  int n = *novf;
  for (int i = blockIdx.x * blockDim.x + threadIdx.x; i < n;
       i += gridDim.x * blockDim.x) {
    unsigned long long v = ovf[i];
    int d = (int)(v >> 32);
    int s = (int)(v & 0xffffffffull);
    int p = offs[d] + atomicAdd(&fillc[d], 1);
    csr[p] = s;
  }
}

__global__ __launch_bounds__(256) void fillwin_kernel(
    const unsigned long long* __restrict__ bpairs, const int* __restrict__ gcount,
    const int* __restrict__ offs, int* __restrict__ fillc, int* __restrict__ csr) {
  __shared__ int win[WCAP];
  __shared__ int nfill[256];
  const int b = blockIdx.x;
  const int nlo = b << BK_SHIFT;
  const int nhi = min(nlo + 256, NNODES);
  const int base = offs[nlo];
  const int W = offs[nhi] - base;
  int cnt = gcount[b];
  if (cnt > BCAP) cnt = BCAP;
  if (W <= WCAP) {
    if ((int)threadIdx.x < nhi - nlo) nfill[threadIdx.x] = fillc[nlo + threadIdx.x];
    // preserve any ovf-scattered cells
    for (int i = threadIdx.x; i < W; i += 256) win[i] = csr[base + i];
    __syncthreads();
    for (int i = threadIdx.x; i < cnt; i += 256) {
      unsigned long long v = bpairs[(size_t)b * BCAP + i];
      int d = (int)(v >> 32);
      int s = (int)(v & 0xffffffffull);
      int p = offs[d] - base + atomicAdd(&nfill[d - nlo], 1);
      win[p] = s;
    }
    __syncthreads();
    for (int i = threadIdx.x; i < W; i += 256) csr[base + i] = win[i];
  } else {
    // window overflow: direct scatter (continues fillc from ovf_scatter)
    for (int i = threadIdx.x; i < cnt; i += 256) {
      unsigned long long v = bpairs[(size_t)b * BCAP + i];
      int d = (int)(v >> 32);
      int s = (int)(v & 0xffffffffull);
      int p = offs[d] + atomicAdd(&fillc[d], 1);
      csr[p] = s;
    }
  }
}

// ---------------------------------------------------------------- fp32 -> fp16 convert

__global__ void xcvt_kernel(const float* __restrict__ x, f16x4* __restrict__ y, int n4) {
  int i = blockIdx.x * blockDim.x + threadIdx.x;
  if (i >= n4) return;
  float4 v = ((const float4*)x)[i];
  f16x4 h;
  h[0] = (_Float16)v.x;
  h[1] = (_Float16)v.y;
  h[2] = (_Float16)v.z;
  h[3] = (_Float16)v.w;
  y[i] = h;
}

// fused convert + prescale: one pass over x_neighbor produces xn16 (unscaled)
// and ybuf (dinv-scaled) — saves prescale16's separate 51 MB pass.
__global__ void xcvt2_kernel(const float* __restrict__ x, const float* __restrict__ dinv,
                             f16x4* __restrict__ xn, f16x4* __restrict__ yb) {
  int i = blockIdx.x * blockDim.x + threadIdx.x;  // over NNODES*32 float4
  if (i >= NNODES * 32) return;
  int row = i >> 5;
  float s = dinv[row];
  float4 v = ((const float4*)x)[i];
  f16x4 h, hp;
  h[0] = (_Float16)v.x;
  h[1] = (_Float16)v.y;
  h[2] = (_Float16)v.z;
  h[3] = (_Float16)v.w;
  hp[0] = (_Float16)(v.x * s);
  hp[1] = (_Float16)(v.y * s);
  hp[2] = (_Float16)(v.z * s);
  hp[3] = (_Float16)(v.w * s);
  xn[i] = h;
  yb[i] = hp;
}

// ---------------------------------------------------------------- aggregation (gather, fp16 in)
// r10 form (REVERTED from r11's 16B/lane restructure, which regressed 68->88us:
// gather is MLP-bound — 8 full-wave loads in flight beats 4 wide loads, and the
// 16B/lane tail crawled for the ~half of nodes with deg<16).
// Input rows are PRE-SCALED fp16: y_j = (fp16)(dinv[j]*x_j).   256 B/row.
// out[i,:] = dinv[i] * (y_i + sum_{j in nbr(i)} y_j) + bias   (fp32 accumulate)
// One wave per node, f16x2 per lane, 8-way unrolled gathers (4 fp32 accumulators).

__device__ __forceinline__ float2 f16x2_to_f32(f16x2 h) {
  return make_float2((float)h[0], (float)h[1]);
}

__global__ __launch_bounds__(256) void aggregate_half_kernel(
    const f16x2* __restrict__ in, void* __restrict__ out, int out_half,
    const int* __restrict__ offs, const int* __restrict__ csr, const float* __restrict__ dinv,
    const float* __restrict__ bias) {
  int node = blockIdx.x * 4 + (threadIdx.x >> 6);
  if (node >= NNODES) return;
  int ch = threadIdx.x & 63;  // f16x2 index within row (64 x f16x2 = 128 cols)
  int beg = offs[node], end = offs[node + 1];

  // self term (pre-scaled row)
  float2 a0 = f16x2_to_f32(in[(size_t)node * 64 + ch]);
  float2 a1 = make_float2(0.f, 0.f);
  float2 a2 = make_float2(0.f, 0.f);
  float2 a3 = make_float2(0.f, 0.f);

  int p = beg;
  for (; p + 8 <= end; p += 8) {
    int j0 = csr[p + 0], j1 = csr[p + 1], j2 = csr[p + 2], j3 = csr[p + 3];
    int j4 = csr[p + 4], j5 = csr[p + 5], j6 = csr[p + 6], j7 = csr[p + 7];
    f16x2 h0 = in[(size_t)j0 * 64 + ch];
    f16x2 h1 = in[(size_t)j1 * 64 + ch];
    f16x2 h2 = in[(size_t)j2 * 64 + ch];
    f16x2 h3 = in[(size_t)j3 * 64 + ch];
    f16x2 h4 = in[(size_t)j4 * 64 + ch];
    f16x2 h5 = in[(size_t)j5 * 64 + ch];
    f16x2 h6 = in[(size_t)j6 * 64 + ch];
    f16x2 h7 = in[(size_t)j7 * 64 + ch];
    float2 v0 = f16x2_to_f32(h0);
    float2 v1 = f16x2_to_f32(h1);
    float2 v2 = f16x2_to_f32(h2);
    float2 v3 = f16x2_to_f32(h3);
    float2 v4 = f16x2_to_f32(h4);
    float2 v5 = f16x2_to_f32(h5);
    float2 v6 = f16x2_to_f32(h6);
    float2 v7 = f16x2_to_f32(h7);
    a0.x += v0.x; a0.y += v0.y;
    a1.x += v1.x; a1.y += v1.y;
    a2.x += v2.x; a2.y += v2.y;
    a3.x += v3.x; a3.y += v3.y;
    a0.x += v4.x; a0.y += v4.y;
    a1.x += v5.x; a1.y += v5.y;
    a2.x += v6.x; a2.y += v6.y;
    a3.x += v7.x; a3.y += v7.y;
  }
  for (; p + 2 <= end; p += 2) {
    int j0 = csr[p], j1 = csr[p + 1];
    float2 v0 = f16x2_to_f32(in[(size_t)j0 * 64 + ch]);
    float2 v1 = f16x2_to_f32(in[(size_t)j1 * 64 + ch]);
    a0.x += v0.x; a0.y += v0.y;
    a1.x += v1.x; a1.y += v1.y;
  }
  if (p < end) {
    float2 v0 = f16x2_to_f32(in[(size_t)csr[p] * 64 + ch]);
    a0.x += v0.x; a0.y += v0.y;
  }

  float di = dinv[node];
  int c = ch * 2;
  float2 r;
  r.x = di * (a0.x + a1.x + a2.x + a3.x);
  r.y = di * (a0.y + a1.y + a2.y + a3.y);
  if (bias) {
    r.x += bias[c];
    r.y += bias[c + 1];
  }
  if (out_half) {
    f16x2 h;
    h[0] = (_Float16)r.x;
    h[1] = (_Float16)r.y;
    ((f16x2*)out)[(size_t)node * 64 + ch] = h;
  } else {
    *(float2*)((float*)out + (size_t)node * 128 + c) = r;
  }
}

// ---------------------------------------------------------------- weight prep
// W [K][M] fp32  ->  Wt [M][K] fp16 (transposed).  Single fp16 — wl dropped:
// A is already fp16 (2^-11), wl only polished the smaller error source.

__global__ void wprep_f16_kernel(const float* __restrict__ W, int K, int M,
                                 _Float16* __restrict__ th) {
  int i = blockIdx.x * blockDim.x + threadIdx.x;
  if (i >= K * M) return;
  int k = i / M, m = i - k * M;
  th[(size_t)m * K + k] = (_Float16)W[i];
}

// ---------------------------------------------------------------- fp16 MFMA GEMM
// C[n,M] = concat(A0,A1,A2) @ W (+row_scale)(+bias)(+relu).  All fp16 operands,
// fp32 accumulate, 1 MFMA per tile per K-step.
// 2-PHASE DOUBLE-BUFFERED staging; LDS 32 KB (one smem block: As[2] | Bs[2]).
// EPILOGUE (out_half): LDS-staged coalesced writes (r9 PMC: direct 32B fp16 runs
// caused 2.15x sector amplification; staging removed it, r10 confirmed -62us).

#define BM 128
#define BN 128
#define BK 32

__global__ __launch_bounds__(256) void gemm_f16_kernel(
    const _Float16* __restrict__ A0, int K0, const _Float16* __restrict__ A1, int K1,
    const _Float16* __restrict__ A2, int K2, const _Float16* __restrict__ Bth, int Ktot, int M,
    const float* __restrict__ bias, const float* __restrict__ row_scale,
    void* __restrict__ Cmat, int relu, int out_half, int nrows) {
  __shared__ _Float16 smem[4 * BM * BK];  // 32 KB: As[2] | Bs[2]; reused as C-tile
  _Float16* const As0 = smem;
  _Float16* const Bs0 = smem + 2 * BM * BK;

  const int tid = threadIdx.x;
  const int lane = tid & 63;
  const int wv = tid >> 6;
  const int mBase = (wv >> 1) * 64;
  const int nBase = (wv & 1) * 64;
  const int ml = lane & 15;
  const int quad = lane >> 4;
  const int rowBase = blockIdx.x * BM;
  const int colBase = blockIdx.y * BN;

  // staging geometry: wave wv stages tile rows [wv*32, wv*32+32) of A and B.
  const int lrow = lane >> 2;  // 0..15
  const int lslot = lane & 3;  // 16B slot within 64B row

  f32x4 acc[4][4];
  const f32x4 zero = {0.f, 0.f, 0.f, 0.f};
#pragma unroll
  for (int i = 0; i < 4; i++)
#pragma unroll
    for (int j = 0; j < 4; j++) acc[i][j] = zero;

  auto stage = [&](int k0, int buf) {
    const _Float16* Ap;
    int kl, Kp;
    if (k0 < K0) {
      Ap = A0; kl = k0; Kp = K0;
    } else if (k0 < K0 + K1) {
      Ap = A1; kl = k0 - K0; Kp = K1;
    } else {
      Ap = A2; kl = k0 - K0 - K1; Kp = K2;
    }
    char* Ab = (char*)(As0 + buf * BM * BK);
    char* Bb = (char*)(Bs0 + buf * BN * BK);
#pragma unroll
    for (int c = 0; c < 2; c++) {
      int trow = wv * 32 + c * 16 + lrow;       // tile row 0..127
      int sws = lslot ^ (trow & 3);             // swizzled global 16B slot
      size_t ldsoff = (size_t)(wv * 32 + c * 16) * 64;  // bytes, wave-uniform
      int gr = rowBase + trow;
      if (gr > nrows - 1) gr = nrows - 1;       // clamp: garbage rows skipped on store
      gload_lds16(Ap + (size_t)gr * Kp + kl + sws * 8, Ab + ldsoff);
      gload_lds16(Bth + (size_t)(colBase + trow) * Ktot + k0 + sws * 8, Bb + ldsoff);
    }
  };

  const int ntile = Ktot / BK;
  stage(0, 0);
  __syncthreads();
  int cur = 0;
  for (int t = 0; t < ntile; ++t) {
    if (t + 1 < ntile) stage((t + 1) * BK, cur ^ 1);

    f16x8 av[4], bv[4];
#pragma unroll
    for (int nt = 0; nt < 4; nt++) {
      int nrow = nBase + nt * 16 + ml;
      int boff = nrow * 32 + ((quad ^ (nrow & 3)) << 3);
      bv[nt] = *(const f16x8*)&Bs0[cur * BN * BK + boff];
    }
#pragma unroll
    for (int mt = 0; mt < 4; mt++) {
      int mrow = mBase + mt * 16 + ml;
      int aoff = mrow * 32 + ((quad ^ (mrow & 3)) << 3);
      av[mt] = *(const f16x8*)&As0[cur * BM * BK + aoff];
    }
#pragma unroll
    for (int mt = 0; mt < 4; mt++)
#pragma unroll
      for (int nt = 0; nt < 4; nt++) {
        acc[mt][nt] =
            __builtin_amdgcn_mfma_f32_16x16x32_f16(av[mt], bv[nt], acc[mt][nt], 0, 0, 0);
      }
    __syncthreads();
    cur ^= 1;
  }

  // epilogue: C/D layout col=lane&15, row=quad*4+reg
  if (out_half) {
    // stage full 128x128 fp16 tile in smem (staging bufs dead past final barrier)
    _Float16* Ct = smem;
#pragma unroll
    for (int nt = 0; nt < 4; nt++) {
      int colL = nBase + nt * 16 + ml;
      float bv = bias ? bias[colBase + colL] : 0.f;
#pragma unroll
      for (int mt = 0; mt < 4; mt++) {
        int rowL0 = mBase + mt * 16 + quad * 4;
#pragma unroll
        for (int r = 0; r < 4; r++) {
          int rowL = rowL0 + r;
          int grow = rowBase + rowL;
          float v = acc[mt][nt][r];
          if (row_scale) v *= row_scale[grow < nrows ? grow : nrows - 1];
          v += bv;
          if (relu) v = fmaxf(v, 0.f);
          Ct[rowL * 128 + colL] = (_Float16)v;
        }
      }
    }
    __syncthreads();
    // coalesced copy-out: 128 rows x 256B = 2048 x 16B chunks
    for (int idx = tid; idx < 2048; idx += 256) {
      int rowL = idx >> 4;
      int chunk = idx & 15;
      int grow = rowBase + rowL;
      if (grow < nrows) {
        *(uint4*)((_Float16*)Cmat + (size_t)grow * M + colBase + chunk * 8) =
            *(const uint4*)&Ct[rowL * 128 + chunk * 8];
      }
    }
  } else {
#pragma unroll
    for (int nt = 0; nt < 4; nt++) {
      int col = colBase + nBase + nt * 16 + ml;
      float bv = bias ? bias[col] : 0.f;
#pragma unroll
      for (int mt = 0; mt < 4; mt++) {
        int row0 = rowBase + mBase + mt * 16 + quad * 4;
#pragma unroll
        for (int r = 0; r < 4; r++) {
          int grow = row0 + r;
          if (grow >= nrows) continue;
          float v = acc[mt][nt][r];
          if (row_scale) v *= row_scale[grow];
          v += bv;
          if (relu) v = fmaxf(v, 0.f);
          ((float*)Cmat)[(size_t)grow * M + col] = v;
        }
      }
    }
  }
}

// ---------------------------------------------------------------- launch

extern "C" void kernel_launch(void* const* d_in, const int* in_sizes, int n_in, void* d_out,
                              int out_size, void* d_ws, size_t ws_size, hipStream_t stream) {
  const float* x_self     = (const float*)d_in[0];
  const float* x_neighbor = (const float*)d_in[1];
  const void*  edge_index = d_in[2];
  const float* W_in_self  = (const float*)d_in[3];
  const float* b_in_self  = (const float*)d_in[4];
  const float* W_out_self = (const float*)d_in[5];
  const float* b_out_self = (const float*)d_in[6];
  const float* Wg1        = (const float*)d_in[7];
  const float* bg1        = (const float*)d_in[8];
  const float* Wg2        = (const float*)d_in[9];
  const float* bg2        = (const float*)d_in[10];
  const float* W_out      = (const float*)d_in[11];
  const float* b_out      = (const float*)d_in[12];
  float* out = (float*)d_out;

  char* ws = (char*)d_ws;
  size_t off = 0;
  auto alloc = [&](size_t bytes) -> void* {
    void* p = ws + off;
    off = (off + bytes + 255) & ~(size_t)255;
    return p;
  };
  int* counts = (int*)alloc((size_t)2 * NNODES * 4 + 2048);  // counts+fillc+gcount+novf
  int* fillc  = counts + NNODES;
  int* gcount = counts + 2 * NNODES;         // NBUCK ints
  int* novf   = gcount + NBUCK;              // 1 int (within the 512-int pad)
  int*   offs   = (int*)alloc((size_t)(NNODES + 1) * 4);
  int*   csr    = (int*)alloc((size_t)NEDGES * 4);
  int*   bsums  = (int*)alloc(4096);
  int*   flag   = (int*)alloc(256);
  float* dinv   = (float*)alloc((size_t)NNODES * 4);
  _Float16* wt1 = (_Float16*)alloc(32768 * 2);  // W_in_self  K=128 M=256
  _Float16* wt2 = (_Float16*)alloc(49152 * 2);  // W_out_self K=384 M=128
  _Float16* wt3 = (_Float16*)alloc(32768 * 2);  // Wg1        K=128 M=256
  _Float16* wt4 = (_Float16*)alloc(32768 * 2);  // Wg2        K=256 M=128
  _Float16* wt5 = (_Float16*)alloc(65536 * 2);  // W_out      K=512 M=128
  float* bufA = (float*)alloc((size_t)NNODES * 256 * 4);
  float* bufB = (float*)alloc((size_t)NNODES * 256 * 4);
  (void)ws_size;

  // bpairs (25.6 MB) aliases bufA: dead before GEMM-1 writes l1 there.
  // ovf (12.8 MB) aliases bufB base: dead before xcvt2 writes ybuf there.
  unsigned long long* bpairs = (unsigned long long*)bufA;
  unsigned long long* ovf = (unsigned long long*)bufB;

  const int nb = (NNODES + SCAN_TILE - 1) / SCAN_TILE;  // 98
  const int gridRows = (NNODES + BM - 1) / BM;          // 782

  detect_kernel<<<1, 64, 0, stream>>>((const unsigned int*)edge_index, flag);
  zero_int_kernel<<<(2 * NNODES + 512 + 255) / 256, 256, 0, stream>>>(counts,
                                                                      2 * NNODES + 512);
  bucket_kernel<<<256, 256, 0, stream>>>(edge_index, flag, counts, gcount, bpairs, ovf, novf);
  dinv_kernel<<<(NNODES + 255) / 256, 256, 0, stream>>>(counts, dinv);
  scan_reduce_kernel<<<nb, SCAN_B, 0, stream>>>(counts, bsums);
  scan_bsums_kernel<<<1, 64, 0, stream>>>(bsums, offs, nb);
  scan_write_kernel<<<nb, SCAN_B, 0, stream>>>(counts, bsums, offs);
  ovf_scatter_kernel<<<64, 256, 0, stream>>>(ovf, novf, offs, fillc, csr);
  fillwin_kernel<<<NBUCK, 256, 0, stream>>>(bpairs, gcount, offs, fillc, csr);

  wprep_f16_kernel<<<(32768 + 255) / 256, 256, 0, stream>>>(W_in_self, 128, 256, wt1);
  wprep_f16_kernel<<<(49152 + 255) / 256, 256, 0, stream>>>(W_out_self, 384, 128, wt2);
  wprep_f16_kernel<<<(32768 + 255) / 256, 256, 0, stream>>>(Wg1, 128, 256, wt3);
  wprep_f16_kernel<<<(32768 + 255) / 256, 256, 0, stream>>>(Wg2, 256, 128, wt4);
  wprep_f16_kernel<<<(65536 + 255) / 256, 256, 0, stream>>>(W_out, 512, 128, wt5);

  // ---- fp16 copies of the fp32 inputs (in bufB's permanently-free top half) ----
  _Float16* xs16 = (_Float16*)(bufB + (size_t)NNODES * 128);
  _Float16* xn16 = xs16 + (size_t)NNODES * 128;
  _Float16* ybuf = (_Float16*)bufB;  // dinv-scaled x_neighbor (overwrites dead ovf)
  xcvt_kernel<<<(NNODES * 32 + 255) / 256, 256, 0, stream>>>(x_self, (f16x4*)xs16, NNODES * 32);
  xcvt2_kernel<<<(NNODES * 32 + 255) / 256, 256, 0, stream>>>(x_neighbor, dinv, (f16x4*)xn16,
                                                              (f16x4*)ybuf);

  // ---- dense self branch ----
  // l1 = relu(xs16 @ W1 + b1) stored fp16 [N,256] in bufA (bpairs dead by now)
  _Float16* l1 = (_Float16*)bufA;
  gemm_f16_kernel<<<dim3(gridRows, 2), 256, 0, stream>>>(
      xs16, 128, nullptr, 0, nullptr, 0, wt1, 128, 256, b_in_self, nullptr, l1, 1, 1, NNODES);
  gemm_f16_kernel<<<dim3(gridRows, 1), 256, 0, stream>>>(
      xs16, 128, l1, 256, nullptr, 0, wt2, 384, 128, b_out_self, nullptr, out, 0, 0, NNODES);

  // ---- GCN branch (A_norm @ (X W) == (A_norm @ X) W), all intermediates fp16 ----
  _Float16* aggx = (_Float16*)bufA;
  _Float16* g1   = (_Float16*)bufB;
  _Float16* xw2  = (_Float16*)bufA;
  _Float16* g2   = (_Float16*)bufA + (size_t)NNODES * 128;

  aggregate_half_kernel<<<NNODES / 4, 256, 0, stream>>>((const f16x2*)ybuf, aggx, 1, offs, csr,
                                                        dinv, nullptr);
  gemm_f16_kernel<<<dim3(gridRows, 2), 256, 0, stream>>>(
      aggx, 128, nullptr, 0, nullptr, 0, wt3, 128, 256, bg1, nullptr, g1, 0, 1, NNODES);
  // xw2 = (fp16)((g1 @ Wg2) * dinv[row])  (pre-scale for agg2 folded into epilogue)
  gemm_f16_kernel<<<dim3(gridRows, 1), 256, 0, stream>>>(
      g1, 256, nullptr, 0, nullptr, 0, wt4, 256, 128, nullptr, dinv, xw2, 0, 1, NNODES);
  aggregate_half_kernel<<<NNODES / 4, 256, 0, stream>>>((const f16x2*)xw2, g2, 1, offs, csr,
                                                        dinv, bg2);
  gemm_f16_kernel<<<dim3(gridRows, 1), 256, 0, stream>>>(
      xn16, 128, g1, 256, g2, 128, wt5, 512, 128, b_out, nullptr,
      out + (size_t)NNODES * 128, 0, 0, NNODES);
}

// Round 13
// 651.329 us; speedup vs baseline: 1.0704x; 1.0138x over previous
//
#include <hip/hip_runtime.h>
#include <cstdint>
#include <cstddef>

#define NNODES 100000
#define NEDGES 1600000
// D = 128, C = 128 (hard-coded below)

typedef float f32x4 __attribute__((ext_vector_type(4)));
typedef unsigned int u32;
// native fp16 (no hip_fp16.h dependency — clang _Float16)
typedef _Float16 f16x2 __attribute__((ext_vector_type(2)));
typedef _Float16 f16x4 __attribute__((ext_vector_type(4)));
typedef _Float16 f16x8 __attribute__((ext_vector_type(8)));

// async global->LDS, 16B per lane: dest = lds_base + lane*16 (linear), src per-lane.
__device__ __forceinline__ void gload_lds16(const void* g, void* l) {
  __builtin_amdgcn_global_load_lds((const __attribute__((address_space(1))) u32*)g,
                                   (__attribute__((address_space(3))) u32*)l, 16, 0, 0);
}

// ---------------------------------------------------------------- utilities

__global__ void zero_int_kernel(int* __restrict__ p, int n) {
  int i = blockIdx.x * blockDim.x + threadIdx.x;
  if (i < n) p[i] = 0;
}

// int64 vs int32 edge_index detection (high words all zero => int64)
__global__ void detect_kernel(const unsigned int* __restrict__ ei, int* __restrict__ flag) {
  unsigned int v = ei[2 * threadIdx.x + 1];
  unsigned long long b = __ballot(v != 0u);
  if (threadIdx.x == 0) *flag = (b == 0ull) ? 1 : 0;
}

__device__ __forceinline__ int edge_val(const void* ei, int is64, long long idx) {
  if (is64) return (int)((const long long*)ei)[idx];
  return ((const int*)ei)[idx];
}

// ---------------------------------------------------------------- degree

__global__ void dinv_kernel(const int* __restrict__ counts, float* __restrict__ dinv) {
  int i = blockIdx.x * blockDim.x + threadIdx.x;
  if (i < NNODES) dinv[i] = rsqrtf((float)(counts[i] + 1));  // +1 self loop
}

#define SCAN_B 256
#define SCAN_TILE 1024

__global__ void scan_reduce_kernel(const int* __restrict__ counts, int* __restrict__ bsums) {
  __shared__ int sd[SCAN_B];
  int t = threadIdx.x;
  int base = blockIdx.x * SCAN_TILE + t * 4;
  int s = 0;
#pragma unroll
  for (int i = 0; i < 4; i++) {
    int idx = base + i;
    if (idx < NNODES) s += counts[idx];
  }
  sd[t] = s;
  __syncthreads();
  for (int o = SCAN_B / 2; o > 0; o >>= 1) {
    if (t < o) sd[t] += sd[t + o];
    __syncthreads();
  }
  if (t == 0) bsums[blockIdx.x] = sd[0];
}

__global__ void scan_bsums_kernel(int* __restrict__ bsums, int* __restrict__ offs, int nb) {
  if (threadIdx.x == 0 && blockIdx.x == 0) {
    int run = 0;
    for (int b = 0; b < nb; b++) {
      int v = bsums[b];
      bsums[b] = run;
      run += v;
    }
    offs[NNODES] = run;
  }
}

__global__ void scan_write_kernel(const int* __restrict__ counts, const int* __restrict__ bsums,
                                  int* __restrict__ offs) {
  __shared__ int sd[SCAN_B];
  int t = threadIdx.x;
  int base = blockIdx.x * SCAN_TILE + t * 4;
  int v[4];
  int s = 0;
#pragma unroll
  for (int i = 0; i < 4; i++) {
    int idx = base + i;
    v[i] = (idx < NNODES) ? counts[idx] : 0;
    s += v[i];
  }
  sd[t] = s;
  __syncthreads();
  for (int o = 1; o < SCAN_B; o <<= 1) {
    int x = (t >= o) ? sd[t - o] : 0;
    __syncthreads();
    sd[t] += x;
    __syncthreads();
  }
  int run = sd[t] - s + bsums[blockIdx.x];
#pragma unroll
  for (int i = 0; i < 4; i++) {
    int idx = base + i;
    if (idx < NNODES) {
      offs[idx] = run;
      run += v[i];
    }
  }
}

// ---------------------------------------------------------------- bucketed CSR fill
// Pass A (bucket_kernel): partition edges into 391 dst-buckets of 256 nodes each,
//   AND histogram global degree counts. 256 blocks x 1024 THREADS (r12 PMC showed
//   10% occupancy at 256x256 — latency-bound with nothing busy; 1024 threads gives
//   16 waves/CU without changing per-(block,bucket) run lengths / write pattern).
//   Bucket overflow pairs go to the ovf list (drained after the scan).
// Pass B (fillwin_kernel): block b owns csr window [offs[b*256], offs[(b+1)*256));
//   scatter inside LDS, write back fully coalesced.

#define BK_SHIFT 8
#define NBUCK 391   // ceil(NNODES / 256)
#define BCAP 8192   // pairs per bucket (mean 4096, +64 sigma)
#define WCAP 12288  // csr window ints in LDS (mean 4096, +128 sigma)

__global__ __launch_bounds__(1024) void bucket_kernel(
    const void* __restrict__ ei, const int* __restrict__ flag, int* __restrict__ counts,
    int* __restrict__ gcount, unsigned long long* __restrict__ bpairs,
    unsigned long long* __restrict__ ovf, int* __restrict__ novf) {
  __shared__ int lcount[NBUCK];
  __shared__ int gbase[NBUCK];
  __shared__ int lcur[NBUCK];
  const int is64 = *flag;
  const int chunk = NEDGES / 256;  // 6250 (grid must be 256 blocks)
  const long long e0 = (long long)blockIdx.x * chunk;
  const long long e1 = e0 + chunk;
  for (int i = threadIdx.x; i < NBUCK; i += 1024) {
    lcount[i] = 0;
    lcur[i] = 0;
  }
  __syncthreads();
  for (long long e = e0 + threadIdx.x; e < e1; e += 1024) {
    int d = edge_val(ei, is64, NEDGES + e);
    atomicAdd(&lcount[d >> BK_SHIFT], 1);
    atomicAdd(&counts[d], 1);  // global degree histogram
  }
  __syncthreads();
  for (int i = threadIdx.x; i < NBUCK; i += 1024) {
    int c = lcount[i];
    gbase[i] = c ? atomicAdd(&gcount[i], c) : 0;
  }
  __syncthreads();
  for (long long e = e0 + threadIdx.x; e < e1; e += 1024) {
    int s = edge_val(ei, is64, e);
    int d = edge_val(ei, is64, NEDGES + e);
    int b = d >> BK_SHIFT;
    int pos = gbase[b] + atomicAdd(&lcur[b], 1);
    unsigned long long pair = ((unsigned long long)(unsigned)d << 32) | (unsigned)s;
    if (pos < BCAP) {
      bpairs[(size_t)b * BCAP + pos] = pair;
    } else {
      // bucket overflow: append to ovf list (capacity NEDGES — always fits)
      int o = atomicAdd(novf, 1);
      ovf[o] = pair;
    }
  }
}

// drain overflow pairs (novf == 0 for Poisson(16) input — exits immediately)
__global__ void ovf_scatter_kernel(const unsigned long long* __restrict__ ovf,
                                   const int* __restrict__ novf, const int* __restrict__ offs,
                                   int* __restrict__ fillc, int* __restrict__ csr) {
  int n = *novf;
  for (int i = blockIdx.x * blockDim.x + threadIdx.x; i < n;
       i += gridDim.x * blockDim.x) {
    unsigned long long v = ovf[i];
    int d = (int)(v >> 32);
    int s = (int)(v & 0xffffffffull);
    int p = offs[d] + atomicAdd(&fillc[d], 1);
    csr[p] = s;
  }
}

__global__ __launch_bounds__(256) void fillwin_kernel(
    const unsigned long long* __restrict__ bpairs, const int* __restrict__ gcount,
    const int* __restrict__ offs, int* __restrict__ fillc, int* __restrict__ csr) {
  __shared__ int win[WCAP];
  __shared__ int nfill[256];
  const int b = blockIdx.x;
  const int nlo = b << BK_SHIFT;
  const int nhi = min(nlo + 256, NNODES);
  const int base = offs[nlo];
  const int W = offs[nhi] - base;
  int cnt = gcount[b];
  if (cnt > BCAP) cnt = BCAP;
  if (W <= WCAP) {
    if ((int)threadIdx.x < nhi - nlo) nfill[threadIdx.x] = fillc[nlo + threadIdx.x];
    // preserve any ovf-scattered cells
    for (int i = threadIdx.x; i < W; i += 256) win[i] = csr[base + i];
    __syncthreads();
    for (int i = threadIdx.x; i < cnt; i += 256) {
      unsigned long long v = bpairs[(size_t)b * BCAP + i];
      int d = (int)(v >> 32);
      int s = (int)(v & 0xffffffffull);
      int p = offs[d] - base + atomicAdd(&nfill[d - nlo], 1);
      win[p] = s;
    }
    __syncthreads();
    for (int i = threadIdx.x; i < W; i += 256) csr[base + i] = win[i];
  } else {
    // window overflow: direct scatter (continues fillc from ovf_scatter)
    for (int i = threadIdx.x; i < cnt; i += 256) {
      unsigned long long v = bpairs[(size_t)b * BCAP + i];
      int d = (int)(v >> 32);
      int s = (int)(v & 0xffffffffull);
      int p = offs[d] + atomicAdd(&fillc[d], 1);
      csr[p] = s;
    }
  }
}

// ---------------------------------------------------------------- fp32 -> fp16 convert

__global__ void xcvt_kernel(const float* __restrict__ x, f16x4* __restrict__ y, int n4) {
  int i = blockIdx.x * blockDim.x + threadIdx.x;
  if (i >= n4) return;
  float4 v = ((const float4*)x)[i];
  f16x4 h;
  h[0] = (_Float16)v.x;
  h[1] = (_Float16)v.y;
  h[2] = (_Float16)v.z;
  h[3] = (_Float16)v.w;
  y[i] = h;
}

// fused convert + prescale: one pass over x_neighbor produces xn16 (unscaled)
// and ybuf (dinv-scaled) — saves prescale16's separate 51 MB pass.
__global__ void xcvt2_kernel(const float* __restrict__ x, const float* __restrict__ dinv,
                             f16x4* __restrict__ xn, f16x4* __restrict__ yb) {
  int i = blockIdx.x * blockDim.x + threadIdx.x;  // over NNODES*32 float4
  if (i >= NNODES * 32) return;
  int row = i >> 5;
  float s = dinv[row];
  float4 v = ((const float4*)x)[i];
  f16x4 h, hp;
  h[0] = (_Float16)v.x;
  h[1] = (_Float16)v.y;
  h[2] = (_Float16)v.z;
  h[3] = (_Float16)v.w;
  hp[0] = (_Float16)(v.x * s);
  hp[1] = (_Float16)(v.y * s);
  hp[2] = (_Float16)(v.z * s);
  hp[3] = (_Float16)(v.w * s);
  xn[i] = h;
  yb[i] = hp;
}

// ---------------------------------------------------------------- aggregation (gather, fp16 in)
// r10 form (r11's 16B/lane restructure regressed 68->88us: gather is MLP-bound —
// 8 full-wave loads in flight beats 4 wide loads; 16B/lane tail crawled for
// deg<16 nodes).
// Input rows are PRE-SCALED fp16: y_j = (fp16)(dinv[j]*x_j).   256 B/row.
// out[i,:] = dinv[i] * (y_i + sum_{j in nbr(i)} y_j) + bias   (fp32 accumulate)
// One wave per node, f16x2 per lane, 8-way unrolled gathers (4 fp32 accumulators).

__device__ __forceinline__ float2 f16x2_to_f32(f16x2 h) {
  return make_float2((float)h[0], (float)h[1]);
}

__global__ __launch_bounds__(256) void aggregate_half_kernel(
    const f16x2* __restrict__ in, void* __restrict__ out, int out_half,
    const int* __restrict__ offs, const int* __restrict__ csr, const float* __restrict__ dinv,
    const float* __restrict__ bias) {
  int node = blockIdx.x * 4 + (threadIdx.x >> 6);
  if (node >= NNODES) return;
  int ch = threadIdx.x & 63;  // f16x2 index within row (64 x f16x2 = 128 cols)
  int beg = offs[node], end = offs[node + 1];

  // self term (pre-scaled row)
  float2 a0 = f16x2_to_f32(in[(size_t)node * 64 + ch]);
  float2 a1 = make_float2(0.f, 0.f);
  float2 a2 = make_float2(0.f, 0.f);
  float2 a3 = make_float2(0.f, 0.f);

  int p = beg;
  for (; p + 8 <= end; p += 8) {
    int j0 = csr[p + 0], j1 = csr[p + 1], j2 = csr[p + 2], j3 = csr[p + 3];
    int j4 = csr[p + 4], j5 = csr[p + 5], j6 = csr[p + 6], j7 = csr[p + 7];
    f16x2 h0 = in[(size_t)j0 * 64 + ch];
    f16x2 h1 = in[(size_t)j1 * 64 + ch];
    f16x2 h2 = in[(size_t)j2 * 64 + ch];
    f16x2 h3 = in[(size_t)j3 * 64 + ch];
    f16x2 h4 = in[(size_t)j4 * 64 + ch];
    f16x2 h5 = in[(size_t)j5 * 64 + ch];
    f16x2 h6 = in[(size_t)j6 * 64 + ch];
    f16x2 h7 = in[(size_t)j7 * 64 + ch];
    float2 v0 = f16x2_to_f32(h0);
    float2 v1 = f16x2_to_f32(h1);
    float2 v2 = f16x2_to_f32(h2);
    float2 v3 = f16x2_to_f32(h3);
    float2 v4 = f16x2_to_f32(h4);
    float2 v5 = f16x2_to_f32(h5);
    float2 v6 = f16x2_to_f32(h6);
    float2 v7 = f16x2_to_f32(h7);
    a0.x += v0.x; a0.y += v0.y;
    a1.x += v1.x; a1.y += v1.y;
    a2.x += v2.x; a2.y += v2.y;
    a3.x += v3.x; a3.y += v3.y;
    a0.x += v4.x; a0.y += v4.y;
    a1.x += v5.x; a1.y += v5.y;
    a2.x += v6.x; a2.y += v6.y;
    a3.x += v7.x; a3.y += v7.y;
  }
  for (; p + 2 <= end; p += 2) {
    int j0 = csr[p], j1 = csr[p + 1];
    float2 v0 = f16x2_to_f32(in[(size_t)j0 * 64 + ch]);
    float2 v1 = f16x2_to_f32(in[(size_t)j1 * 64 + ch]);
    a0.x += v0.x; a0.y += v0.y;
    a1.x += v1.x; a1.y += v1.y;
  }
  if (p < end) {
    float2 v0 = f16x2_to_f32(in[(size_t)csr[p] * 64 + ch]);
    a0.x += v0.x; a0.y += v0.y;
  }

  float di = dinv[node];
  int c = ch * 2;
  float2 r;
  r.x = di * (a0.x + a1.x + a2.x + a3.x);
  r.y = di * (a0.y + a1.y + a2.y + a3.y);
  if (bias) {
    r.x += bias[c];
    r.y += bias[c + 1];
  }
  if (out_half) {
    f16x2 h;
    h[0] = (_Float16)r.x;
    h[1] = (_Float16)r.y;
    ((f16x2*)out)[(size_t)node * 64 + ch] = h;
  } else {
    *(float2*)((float*)out + (size_t)node * 128 + c) = r;
  }
}

// ---------------------------------------------------------------- weight prep
// W [K][M] fp32  ->  Wt [M][K] fp16 (transposed).  Single fp16 — wl dropped:
// A is already fp16 (2^-11), wl only polished the smaller error source.

__global__ void wprep_f16_kernel(const float* __restrict__ W, int K, int M,
                                 _Float16* __restrict__ th) {
  int i = blockIdx.x * blockDim.x + threadIdx.x;
  if (i >= K * M) return;
  int k = i / M, m = i - k * M;
  th[(size_t)m * K + k] = (_Float16)W[i];
}

// ---------------------------------------------------------------- fp16 MFMA GEMM
// C[n,M] = concat(A0,A1,A2) @ W (+row_scale)(+bias)(+relu).  All fp16 operands,
// fp32 accumulate, 1 MFMA per tile per K-step.
// 2-PHASE DOUBLE-BUFFERED staging; LDS 32 KB (one smem block: As[2] | Bs[2]).
// EPILOGUE (out_half): LDS-staged coalesced writes (r9 PMC: direct 32B fp16 runs
// caused 2.15x sector amplification; staging removed it, r10 confirmed -62us).

#define BM 128
#define BN 128
#define BK 32

__global__ __launch_bounds__(256) void gemm_f16_kernel(
    const _Float16* __restrict__ A0, int K0, const _Float16* __restrict__ A1, int K1,
    const _Float16* __restrict__ A2, int K2, const _Float16* __restrict__ Bth, int Ktot, int M,
    const float* __restrict__ bias, const float* __restrict__ row_scale,
    void* __restrict__ Cmat, int relu, int out_half, int nrows) {
  __shared__ _Float16 smem[4 * BM * BK];  // 32 KB: As[2] | Bs[2]; reused as C-tile
  _Float16* const As0 = smem;
  _Float16* const Bs0 = smem + 2 * BM * BK;

  const int tid = threadIdx.x;
  const int lane = tid & 63;
  const int wv = tid >> 6;
  const int mBase = (wv >> 1) * 64;
  const int nBase = (wv & 1) * 64;
  const int ml = lane & 15;
  const int quad = lane >> 4;
  const int rowBase = blockIdx.x * BM;
  const int colBase = blockIdx.y * BN;

  // staging geometry: wave wv stages tile rows [wv*32, wv*32+32) of A and B.
  const int lrow = lane >> 2;  // 0..15
  const int lslot = lane & 3;  // 16B slot within 64B row

  f32x4 acc[4][4];
  const f32x4 zero = {0.f, 0.f, 0.f, 0.f};
#pragma unroll
  for (int i = 0; i < 4; i++)
#pragma unroll
    for (int j = 0; j < 4; j++) acc[i][j] = zero;

  auto stage = [&](int k0, int buf) {
    const _Float16* Ap;
    int kl, Kp;
    if (k0 < K0) {
      Ap = A0; kl = k0; Kp = K0;
    } else if (k0 < K0 + K1) {
      Ap = A1; kl = k0 - K0; Kp = K1;
    } else {
      Ap = A2; kl = k0 - K0 - K1; Kp = K2;
    }
    char* Ab = (char*)(As0 + buf * BM * BK);
    char* Bb = (char*)(Bs0 + buf * BN * BK);
#pragma unroll
    for (int c = 0; c < 2; c++) {
      int trow = wv * 32 + c * 16 + lrow;       // tile row 0..127
      int sws = lslot ^ (trow & 3);             // swizzled global 16B slot
      size_t ldsoff = (size_t)(wv * 32 + c * 16) * 64;  // bytes, wave-uniform
      int gr = rowBase + trow;
      if (gr > nrows - 1) gr = nrows - 1;       // clamp: garbage rows skipped on store
      gload_lds16(Ap + (size_t)gr * Kp + kl + sws * 8, Ab + ldsoff);
      gload_lds16(Bth + (size_t)(colBase + trow) * Ktot + k0 + sws * 8, Bb + ldsoff);
    }
  };

  const int ntile = Ktot / BK;
  stage(0, 0);
  __syncthreads();
  int cur = 0;
  for (int t = 0; t < ntile; ++t) {
    if (t + 1 < ntile) stage((t + 1) * BK, cur ^ 1);

    f16x8 av[4], bv[4];
#pragma unroll
    for (int nt = 0; nt < 4; nt++) {
      int nrow = nBase + nt * 16 + ml;
      int boff = nrow * 32 + ((quad ^ (nrow & 3)) << 3);
      bv[nt] = *(const f16x8*)&Bs0[cur * BN * BK + boff];
    }
#pragma unroll
    for (int mt = 0; mt < 4; mt++) {
      int mrow = mBase + mt * 16 + ml;
      int aoff = mrow * 32 + ((quad ^ (mrow & 3)) << 3);
      av[mt] = *(const f16x8*)&As0[cur * BM * BK + aoff];
    }
#pragma unroll
    for (int mt = 0; mt < 4; mt++)
#pragma unroll
      for (int nt = 0; nt < 4; nt++) {
        acc[mt][nt] =
            __builtin_amdgcn_mfma_f32_16x16x32_f16(av[mt], bv[nt], acc[mt][nt], 0, 0, 0);
      }
    __syncthreads();
    cur ^= 1;
  }

  // epilogue: C/D layout col=lane&15, row=quad*4+reg
  if (out_half) {
    // stage full 128x128 fp16 tile in smem (staging bufs dead past final barrier)
    _Float16* Ct = smem;
#pragma unroll
    for (int nt = 0; nt < 4; nt++) {
      int colL = nBase + nt * 16 + ml;
      float bv = bias ? bias[colBase + colL] : 0.f;
#pragma unroll
      for (int mt = 0; mt < 4; mt++) {
        int rowL0 = mBase + mt * 16 + quad * 4;
#pragma unroll
        for (int r = 0; r < 4; r++) {
          int rowL = rowL0 + r;
          int grow = rowBase + rowL;
          float v = acc[mt][nt][r];
          if (row_scale) v *= row_scale[grow < nrows ? grow : nrows - 1];
          v += bv;
          if (relu) v = fmaxf(v, 0.f);
          Ct[rowL * 128 + colL] = (_Float16)v;
        }
      }
    }
    __syncthreads();
    // coalesced copy-out: 128 rows x 256B = 2048 x 16B chunks
    for (int idx = tid; idx < 2048; idx += 256) {
      int rowL = idx >> 4;
      int chunk = idx & 15;
      int grow = rowBase + rowL;
      if (grow < nrows) {
        *(uint4*)((_Float16*)Cmat + (size_t)grow * M + colBase + chunk * 8) =
            *(const uint4*)&Ct[rowL * 128 + chunk * 8];
      }
    }
  } else {
#pragma unroll
    for (int nt = 0; nt < 4; nt++) {
      int col = colBase + nBase + nt * 16 + ml;
      float bv = bias ? bias[col] : 0.f;
#pragma unroll
      for (int mt = 0; mt < 4; mt++) {
        int row0 = rowBase + mBase + mt * 16 + quad * 4;
#pragma unroll
        for (int r = 0; r < 4; r++) {
          int grow = row0 + r;
          if (grow >= nrows) continue;
          float v = acc[mt][nt][r];
          if (row_scale) v *= row_scale[grow];
          v += bv;
          if (relu) v = fmaxf(v, 0.f);
          ((float*)Cmat)[(size_t)grow * M + col] = v;
        }
      }
    }
  }
}

// ---------------------------------------------------------------- launch

extern "C" void kernel_launch(void* const* d_in, const int* in_sizes, int n_in, void* d_out,
                              int out_size, void* d_ws, size_t ws_size, hipStream_t stream) {
  const float* x_self     = (const float*)d_in[0];
  const float* x_neighbor = (const float*)d_in[1];
  const void*  edge_index = d_in[2];
  const float* W_in_self  = (const float*)d_in[3];
  const float* b_in_self  = (const float*)d_in[4];
  const float* W_out_self = (const float*)d_in[5];
  const float* b_out_self = (const float*)d_in[6];
  const float* Wg1        = (const float*)d_in[7];
  const float* bg1        = (const float*)d_in[8];
  const float* Wg2        = (const float*)d_in[9];
  const float* bg2        = (const float*)d_in[10];
  const float* W_out      = (const float*)d_in[11];
  const float* b_out      = (const float*)d_in[12];
  float* out = (float*)d_out;

  char* ws = (char*)d_ws;
  size_t off = 0;
  auto alloc = [&](size_t bytes) -> void* {
    void* p = ws + off;
    off = (off + bytes + 255) & ~(size_t)255;
    return p;
  };
  int* counts = (int*)alloc((size_t)2 * NNODES * 4 + 2048);  // counts+fillc+gcount+novf
  int* fillc  = counts + NNODES;
  int* gcount = counts + 2 * NNODES;         // NBUCK ints
  int* novf   = gcount + NBUCK;              // 1 int (within the 512-int pad)
  int*   offs   = (int*)alloc((size_t)(NNODES + 1) * 4);
  int*   csr    = (int*)alloc((size_t)NEDGES * 4);
  int*   bsums  = (int*)alloc(4096);
  int*   flag   = (int*)alloc(256);
  float* dinv   = (float*)alloc((size_t)NNODES * 4);
  _Float16* wt1 = (_Float16*)alloc(32768 * 2);  // W_in_self  K=128 M=256
  _Float16* wt2 = (_Float16*)alloc(49152 * 2);  // W_out_self K=384 M=128
  _Float16* wt3 = (_Float16*)alloc(32768 * 2);  // Wg1        K=128 M=256
  _Float16* wt4 = (_Float16*)alloc(32768 * 2);  // Wg2        K=256 M=128
  _Float16* wt5 = (_Float16*)alloc(65536 * 2);  // W_out      K=512 M=128
  float* bufA = (float*)alloc((size_t)NNODES * 256 * 4);
  float* bufB = (float*)alloc((size_t)NNODES * 256 * 4);
  (void)ws_size;

  // bpairs (25.6 MB) aliases bufA: dead before GEMM-1 writes l1 there.
  // ovf (12.8 MB) aliases bufB base: dead before xcvt2 writes ybuf there.
  unsigned long long* bpairs = (unsigned long long*)bufA;
  unsigned long long* ovf = (unsigned long long*)bufB;

  const int nb = (NNODES + SCAN_TILE - 1) / SCAN_TILE;  // 98
  const int gridRows = (NNODES + BM - 1) / BM;          // 782

  detect_kernel<<<1, 64, 0, stream>>>((const unsigned int*)edge_index, flag);
  zero_int_kernel<<<(2 * NNODES + 512 + 255) / 256, 256, 0, stream>>>(counts,
                                                                      2 * NNODES + 512);
  bucket_kernel<<<256, 1024, 0, stream>>>(edge_index, flag, counts, gcount, bpairs, ovf, novf);
  dinv_kernel<<<(NNODES + 255) / 256, 256, 0, stream>>>(counts, dinv);
  scan_reduce_kernel<<<nb, SCAN_B, 0, stream>>>(counts, bsums);
  scan_bsums_kernel<<<1, 64, 0, stream>>>(bsums, offs, nb);
  scan_write_kernel<<<nb, SCAN_B, 0, stream>>>(counts, bsums, offs);
  ovf_scatter_kernel<<<64, 256, 0, stream>>>(ovf, novf, offs, fillc, csr);
  fillwin_kernel<<<NBUCK, 256, 0, stream>>>(bpairs, gcount, offs, fillc, csr);

  wprep_f16_kernel<<<(32768 + 255) / 256, 256, 0, stream>>>(W_in_self, 128, 256, wt1);
  wprep_f16_kernel<<<(49152 + 255) / 256, 256, 0, stream>>>(W_out_self, 384, 128, wt2);
  wprep_f16_kernel<<<(32768 + 255) / 256, 256, 0, stream>>>(Wg1, 128, 256, wt3);
  wprep_f16_kernel<<<(32768 + 255) / 256, 256, 0, stream>>>(Wg2, 256, 128, wt4);
  wprep_f16_kernel<<<(65536 + 255) / 256, 256, 0, stream>>>(W_out, 512, 128, wt5);

  // ---- fp16 copies of the fp32 inputs (in bufB's permanently-free top half) ----
  _Float16* xs16 = (_Float16*)(bufB + (size_t)NNODES * 128);
  _Float16* xn16 = xs16 + (size_t)NNODES * 128;
  _Float16* ybuf = (_Float16*)bufB;  // dinv-scaled x_neighbor (overwrites dead ovf)
  xcvt_kernel<<<(NNODES * 32 + 255) / 256, 256, 0, stream>>>(x_self, (f16x4*)xs16, NNODES * 32);
  xcvt2_kernel<<<(NNODES * 32 + 255) / 256, 256, 0, stream>>>(x_neighbor, dinv, (f16x4*)xn16,
                                                              (f16x4*)ybuf);

  // ---- dense self branch ----
  // l1 = relu(xs16 @ W1 + b1) stored fp16 [N,256] in bufA (bpairs dead by now)
  _Float16* l1 = (_Float16*)bufA;
  gemm_f16_kernel<<<dim3(gridRows, 2), 256, 0, stream>>>(
      xs16, 128, nullptr, 0, nullptr, 0, wt1, 128, 256, b_in_self, nullptr, l1, 1, 1, NNODES);
  gemm_f16_kernel<<<dim3(gridRows, 1), 256, 0, stream>>>(
      xs16, 128, l1, 256, nullptr, 0, wt2, 384, 128, b_out_self, nullptr, out, 0, 0, NNODES);

  // ---- GCN branch (A_norm @ (X W) == (A_norm @ X) W), all intermediates fp16 ----
  _Float16* aggx = (_Float16*)bufA;
  _Float16* g1   = (_Float16*)bufB;
  _Float16* xw2  = (_Float16*)bufA;
  _Float16* g2   = (_Float16*)bufA + (size_t)NNODES * 128;

  aggregate_half_kernel<<<NNODES / 4, 256, 0, stream>>>((const f16x2*)ybuf, aggx, 1, offs, csr,
                                                        dinv, nullptr);
  gemm_f16_kernel<<<dim3(gridRows, 2), 256, 0, stream>>>(
      aggx, 128, nullptr, 0, nullptr, 0, wt3, 128, 256, bg1, nullptr, g1, 0, 1, NNODES);
  // xw2 = (fp16)((g1 @ Wg2) * dinv[row])  (pre-scale for agg2 folded into epilogue)
  gemm_f16_kernel<<<dim3(gridRows, 1), 256, 0, stream>>>(
      g1, 256, nullptr, 0, nullptr, 0, wt4, 256, 128, nullptr, dinv, xw2, 0, 1, NNODES);
  aggregate_half_kernel<<<NNODES / 4, 256, 0, stream>>>((const f16x2*)xw2, g2, 1, offs, csr,
                                                        dinv, bg2);
  gemm_f16_kernel<<<dim3(gridRows, 1), 256, 0, stream>>>(
      xn16, 128, g1, 256, g2, 128, wt5, 512, 128, b_out, nullptr,
      out + (size_t)NNODES * 128, 0, 0, NNODES);
}

// Round 14
// 647.056 us; speedup vs baseline: 1.0774x; 1.0066x over previous
//
#include <hip/hip_runtime.h>
#include <cstdint>
#include <cstddef>

#define NNODES 100000
#define NEDGES 1600000
// D = 128, C = 128 (hard-coded below)

typedef float f32x4 __attribute__((ext_vector_type(4)));
typedef unsigned int u32;
// native fp16 (no hip_fp16.h dependency — clang _Float16)
typedef _Float16 f16x2 __attribute__((ext_vector_type(2)));
typedef _Float16 f16x4 __attribute__((ext_vector_type(4)));
typedef _Float16 f16x8 __attribute__((ext_vector_type(8)));

// async global->LDS, 16B per lane: dest = lds_base + lane*16 (linear), src per-lane.
__device__ __forceinline__ void gload_lds16(const void* g, void* l) {
  __builtin_amdgcn_global_load_lds((const __attribute__((address_space(1))) u32*)g,
                                   (__attribute__((address_space(3))) u32*)l, 16, 0, 0);
}

// ---------------------------------------------------------------- utilities

__global__ void zero_int_kernel(int* __restrict__ p, int n) {
  int i = blockIdx.x * blockDim.x + threadIdx.x;
  if (i < n) p[i] = 0;
}

// int64 vs int32 edge_index detection (high words all zero => int64)
__global__ void detect_kernel(const unsigned int* __restrict__ ei, int* __restrict__ flag) {
  unsigned int v = ei[2 * threadIdx.x + 1];
  unsigned long long b = __ballot(v != 0u);
  if (threadIdx.x == 0) *flag = (b == 0ull) ? 1 : 0;
}

__device__ __forceinline__ int edge_val(const void* ei, int is64, long long idx) {
  if (is64) return (int)((const long long*)ei)[idx];
  return ((const int*)ei)[idx];
}

// ---------------------------------------------------------------- degree

__global__ void dinv_kernel(const int* __restrict__ counts, float* __restrict__ dinv) {
  int i = blockIdx.x * blockDim.x + threadIdx.x;
  if (i < NNODES) dinv[i] = rsqrtf((float)(counts[i] + 1));  // +1 self loop
}

#define SCAN_B 256
#define SCAN_TILE 1024

__global__ void scan_reduce_kernel(const int* __restrict__ counts, int* __restrict__ bsums) {
  __shared__ int sd[SCAN_B];
  int t = threadIdx.x;
  int base = blockIdx.x * SCAN_TILE + t * 4;
  int s = 0;
#pragma unroll
  for (int i = 0; i < 4; i++) {
    int idx = base + i;
    if (idx < NNODES) s += counts[idx];
  }
  sd[t] = s;
  __syncthreads();
  for (int o = SCAN_B / 2; o > 0; o >>= 1) {
    if (t < o) sd[t] += sd[t + o];
    __syncthreads();
  }
  if (t == 0) bsums[blockIdx.x] = sd[0];
}

__global__ void scan_bsums_kernel(int* __restrict__ bsums, int* __restrict__ offs, int nb) {
  if (threadIdx.x == 0 && blockIdx.x == 0) {
    int run = 0;
    for (int b = 0; b < nb; b++) {
      int v = bsums[b];
      bsums[b] = run;
      run += v;
    }
    offs[NNODES] = run;
  }
}

__global__ void scan_write_kernel(const int* __restrict__ counts, const int* __restrict__ bsums,
                                  int* __restrict__ offs) {
  __shared__ int sd[SCAN_B];
  int t = threadIdx.x;
  int base = blockIdx.x * SCAN_TILE + t * 4;
  int v[4];
  int s = 0;
#pragma unroll
  for (int i = 0; i < 4; i++) {
    int idx = base + i;
    v[i] = (idx < NNODES) ? counts[idx] : 0;
    s += v[i];
  }
  sd[t] = s;
  __syncthreads();
  for (int o = 1; o < SCAN_B; o <<= 1) {
    int x = (t >= o) ? sd[t - o] : 0;
    __syncthreads();
    sd[t] += x;
    __syncthreads();
  }
  int run = sd[t] - s + bsums[blockIdx.x];
#pragma unroll
  for (int i = 0; i < 4; i++) {
    int idx = base + i;
    if (idx < NNODES) {
      offs[idx] = run;
      run += v[i];
    }
  }
}

// ---------------------------------------------------------------- bucketed CSR fill
// Pass A (bucket_kernel): partition edges into 391 dst-buckets of 256 nodes each,
//   AND histogram global degree counts. 256 blocks x 1024 threads.
//   r13 PMC: bucket is WRITE-BYTE-BOUND (70 MB scattered writes @0.81 TB/s = its
//   86us; occupancy 4x'd with no speedup). Fix: PACK pairs to 32 bits —
//   (d&255)<<24 | s  (s < 100000 < 2^24; d's high bits = bucket id, implicit).
//   Halves bpairs bytes -> halves sector-amplified HBM writes.
//   Bucket overflow pairs go to the u64 ovf list (drained after the scan).
// Pass B (fillwin_kernel): block b owns csr window [offs[b*256], offs[(b+1)*256));
//   scatter inside LDS, write back fully coalesced.

#define BK_SHIFT 8
#define NBUCK 391   // ceil(NNODES / 256)
#define BCAP 8192   // pairs per bucket (mean 4096, +64 sigma)
#define WCAP 12288  // csr window ints in LDS (mean 4096, +128 sigma)

__global__ __launch_bounds__(1024) void bucket_kernel(
    const void* __restrict__ ei, const int* __restrict__ flag, int* __restrict__ counts,
    int* __restrict__ gcount, unsigned int* __restrict__ bpairs,
    unsigned long long* __restrict__ ovf, int* __restrict__ novf) {
  __shared__ int lcount[NBUCK];
  __shared__ int gbase[NBUCK];
  __shared__ int lcur[NBUCK];
  const int is64 = *flag;
  const int chunk = NEDGES / 256;  // 6250 (grid must be 256 blocks)
  const long long e0 = (long long)blockIdx.x * chunk;
  const long long e1 = e0 + chunk;
  for (int i = threadIdx.x; i < NBUCK; i += 1024) {
    lcount[i] = 0;
    lcur[i] = 0;
  }
  __syncthreads();
  for (long long e = e0 + threadIdx.x; e < e1; e += 1024) {
    int d = edge_val(ei, is64, NEDGES + e);
    atomicAdd(&lcount[d >> BK_SHIFT], 1);
    atomicAdd(&counts[d], 1);  // global degree histogram
  }
  __syncthreads();
  for (int i = threadIdx.x; i < NBUCK; i += 1024) {
    int c = lcount[i];
    gbase[i] = c ? atomicAdd(&gcount[i], c) : 0;
  }
  __syncthreads();
  for (long long e = e0 + threadIdx.x; e < e1; e += 1024) {
    int s = edge_val(ei, is64, e);
    int d = edge_val(ei, is64, NEDGES + e);
    int b = d >> BK_SHIFT;
    int pos = gbase[b] + atomicAdd(&lcur[b], 1);
    if (pos < BCAP) {
      bpairs[(size_t)b * BCAP + pos] =
          ((unsigned)(d & 255) << 24) | (unsigned)s;  // s < 2^24
    } else {
      // bucket overflow: append to ovf list (capacity NEDGES — always fits)
      int o = atomicAdd(novf, 1);
      ovf[o] = ((unsigned long long)(unsigned)d << 32) | (unsigned)s;
    }
  }
}

// drain overflow pairs (novf == 0 for Poisson(16) input — exits immediately)
__global__ void ovf_scatter_kernel(const unsigned long long* __restrict__ ovf,
                                   const int* __restrict__ novf, const int* __restrict__ offs,
                                   int* __restrict__ fillc, int* __restrict__ csr) {
  int n = *novf;
  for (int i = blockIdx.x * blockDim.x + threadIdx.x; i < n;
       i += gridDim.x * blockDim.x) {
    unsigned long long v = ovf[i];
    int d = (int)(v >> 32);
    int s = (int)(v & 0xffffffffull);
    int p = offs[d] + atomicAdd(&fillc[d], 1);
    csr[p] = s;
  }
}

__global__ __launch_bounds__(256) void fillwin_kernel(
    const unsigned int* __restrict__ bpairs, const int* __restrict__ gcount,
    const int* __restrict__ offs, int* __restrict__ fillc, int* __restrict__ csr) {
  __shared__ int win[WCAP];
  __shared__ int nfill[256];
  const int b = blockIdx.x;
  const int nlo = b << BK_SHIFT;
  const int nhi = min(nlo + 256, NNODES);
  const int base = offs[nlo];
  const int W = offs[nhi] - base;
  int cnt = gcount[b];
  if (cnt > BCAP) cnt = BCAP;
  if (W <= WCAP) {
    if ((int)threadIdx.x < nhi - nlo) nfill[threadIdx.x] = fillc[nlo + threadIdx.x];
    // preserve any ovf-scattered cells
    for (int i = threadIdx.x; i < W; i += 256) win[i] = csr[base + i];
    __syncthreads();
    for (int i = threadIdx.x; i < cnt; i += 256) {
      unsigned int v = bpairs[(size_t)b * BCAP + i];
      int dl = (int)(v >> 24);          // d - nlo
      int s = (int)(v & 0xffffffu);
      int p = offs[nlo + dl] - base + atomicAdd(&nfill[dl], 1);
      win[p] = s;
    }
    __syncthreads();
    for (int i = threadIdx.x; i < W; i += 256) csr[base + i] = win[i];
  } else {
    // window overflow: direct scatter (continues fillc from ovf_scatter)
    for (int i = threadIdx.x; i < cnt; i += 256) {
      unsigned int v = bpairs[(size_t)b * BCAP + i];
      int dl = (int)(v >> 24);
      int s = (int)(v & 0xffffffu);
      int d = nlo + dl;
      int p = offs[d] + atomicAdd(&fillc[d], 1);
      csr[p] = s;
    }
  }
}

// ---------------------------------------------------------------- fp32 -> fp16 convert

__global__ void xcvt_kernel(const float* __restrict__ x, f16x4* __restrict__ y, int n4) {
  int i = blockIdx.x * blockDim.x + threadIdx.x;
  if (i >= n4) return;
  float4 v = ((const float4*)x)[i];
  f16x4 h;
  h[0] = (_Float16)v.x;
  h[1] = (_Float16)v.y;
  h[2] = (_Float16)v.z;
  h[3] = (_Float16)v.w;
  y[i] = h;
}

// fused convert + prescale: one pass over x_neighbor produces xn16 (unscaled)
// and ybuf (dinv-scaled) — saves prescale16's separate 51 MB pass.
__global__ void xcvt2_kernel(const float* __restrict__ x, const float* __restrict__ dinv,
                             f16x4* __restrict__ xn, f16x4* __restrict__ yb) {
  int i = blockIdx.x * blockDim.x + threadIdx.x;  // over NNODES*32 float4
  if (i >= NNODES * 32) return;
  int row = i >> 5;
  float s = dinv[row];
  float4 v = ((const float4*)x)[i];
  f16x4 h, hp;
  h[0] = (_Float16)v.x;
  h[1] = (_Float16)v.y;
  h[2] = (_Float16)v.z;
  h[3] = (_Float16)v.w;
  hp[0] = (_Float16)(v.x * s);
  hp[1] = (_Float16)(v.y * s);
  hp[2] = (_Float16)(v.z * s);
  hp[3] = (_Float16)(v.w * s);
  xn[i] = h;
  yb[i] = hp;
}

// ---------------------------------------------------------------- aggregation (gather, fp16 in)
// r10 form (r11's 16B/lane restructure regressed 68->88us: gather is MLP-bound —
// 8 full-wave loads in flight beats 4 wide loads; 16B/lane tail crawled for
// deg<16 nodes).
// Input rows are PRE-SCALED fp16: y_j = (fp16)(dinv[j]*x_j).   256 B/row.
// out[i,:] = dinv[i] * (y_i + sum_{j in nbr(i)} y_j) + bias   (fp32 accumulate)
// One wave per node, f16x2 per lane, 8-way unrolled gathers (4 fp32 accumulators).

__device__ __forceinline__ float2 f16x2_to_f32(f16x2 h) {
  return make_float2((float)h[0], (float)h[1]);
}

__global__ __launch_bounds__(256) void aggregate_half_kernel(
    const f16x2* __restrict__ in, void* __restrict__ out, int out_half,
    const int* __restrict__ offs, const int* __restrict__ csr, const float* __restrict__ dinv,
    const float* __restrict__ bias) {
  int node = blockIdx.x * 4 + (threadIdx.x >> 6);
  if (node >= NNODES) return;
  int ch = threadIdx.x & 63;  // f16x2 index within row (64 x f16x2 = 128 cols)
  int beg = offs[node], end = offs[node + 1];

  // self term (pre-scaled row)
  float2 a0 = f16x2_to_f32(in[(size_t)node * 64 + ch]);
  float2 a1 = make_float2(0.f, 0.f);
  float2 a2 = make_float2(0.f, 0.f);
  float2 a3 = make_float2(0.f, 0.f);

  int p = beg;
  for (; p + 8 <= end; p += 8) {
    int j0 = csr[p + 0], j1 = csr[p + 1], j2 = csr[p + 2], j3 = csr[p + 3];
    int j4 = csr[p + 4], j5 = csr[p + 5], j6 = csr[p + 6], j7 = csr[p + 7];
    f16x2 h0 = in[(size_t)j0 * 64 + ch];
    f16x2 h1 = in[(size_t)j1 * 64 + ch];
    f16x2 h2 = in[(size_t)j2 * 64 + ch];
    f16x2 h3 = in[(size_t)j3 * 64 + ch];
    f16x2 h4 = in[(size_t)j4 * 64 + ch];
    f16x2 h5 = in[(size_t)j5 * 64 + ch];
    f16x2 h6 = in[(size_t)j6 * 64 + ch];
    f16x2 h7 = in[(size_t)j7 * 64 + ch];
    float2 v0 = f16x2_to_f32(h0);
    float2 v1 = f16x2_to_f32(h1);
    float2 v2 = f16x2_to_f32(h2);
    float2 v3 = f16x2_to_f32(h3);
    float2 v4 = f16x2_to_f32(h4);
    float2 v5 = f16x2_to_f32(h5);
    float2 v6 = f16x2_to_f32(h6);
    float2 v7 = f16x2_to_f32(h7);
    a0.x += v0.x; a0.y += v0.y;
    a1.x += v1.x; a1.y += v1.y;
    a2.x += v2.x; a2.y += v2.y;
    a3.x += v3.x; a3.y += v3.y;
    a0.x += v4.x; a0.y += v4.y;
    a1.x += v5.x; a1.y += v5.y;
    a2.x += v6.x; a2.y += v6.y;
    a3.x += v7.x; a3.y += v7.y;
  }
  for (; p + 2 <= end; p += 2) {
    int j0 = csr[p], j1 = csr[p + 1];
    float2 v0 = f16x2_to_f32(in[(size_t)j0 * 64 + ch]);
    float2 v1 = f16x2_to_f32(in[(size_t)j1 * 64 + ch]);
    a0.x += v0.x; a0.y += v0.y;
    a1.x += v1.x; a1.y += v1.y;
  }
  if (p < end) {
    float2 v0 = f16x2_to_f32(in[(size_t)csr[p] * 64 + ch]);
    a0.x += v0.x; a0.y += v0.y;
  }

  float di = dinv[node];
  int c = ch * 2;
  float2 r;
  r.x = di * (a0.x + a1.x + a2.x + a3.x);
  r.y = di * (a0.y + a1.y + a2.y + a3.y);
  if (bias) {
    r.x += bias[c];
    r.y += bias[c + 1];
  }
  if (out_half) {
    f16x2 h;
    h[0] = (_Float16)r.x;
    h[1] = (_Float16)r.y;
    ((f16x2*)out)[(size_t)node * 64 + ch] = h;
  } else {
    *(float2*)((float*)out + (size_t)node * 128 + c) = r;
  }
}

// ---------------------------------------------------------------- weight prep
// W [K][M] fp32  ->  Wt [M][K] fp16 (transposed).  Single fp16 — wl dropped:
// A is already fp16 (2^-11), wl only polished the smaller error source.

__global__ void wprep_f16_kernel(const float* __restrict__ W, int K, int M,
                                 _Float16* __restrict__ th) {
  int i = blockIdx.x * blockDim.x + threadIdx.x;
  if (i >= K * M) return;
  int k = i / M, m = i - k * M;
  th[(size_t)m * K + k] = (_Float16)W[i];
}

// ---------------------------------------------------------------- fp16 MFMA GEMM
// C[n,M] = concat(A0,A1,A2) @ W (+row_scale)(+bias)(+relu).  All fp16 operands,
// fp32 accumulate, 1 MFMA per tile per K-step.
// 2-PHASE DOUBLE-BUFFERED staging; LDS 32 KB (one smem block: As[2] | Bs[2]).
// EPILOGUE (out_half): LDS-staged coalesced writes (r9 PMC: direct 32B fp16 runs
// caused 2.15x sector amplification; staging removed it, r10 confirmed -62us).

#define BM 128
#define BN 128
#define BK 32

__global__ __launch_bounds__(256) void gemm_f16_kernel(
    const _Float16* __restrict__ A0, int K0, const _Float16* __restrict__ A1, int K1,
    const _Float16* __restrict__ A2, int K2, const _Float16* __restrict__ Bth, int Ktot, int M,
    const float* __restrict__ bias, const float* __restrict__ row_scale,
    void* __restrict__ Cmat, int relu, int out_half, int nrows) {
  __shared__ _Float16 smem[4 * BM * BK];  // 32 KB: As[2] | Bs[2]; reused as C-tile
  _Float16* const As0 = smem;
  _Float16* const Bs0 = smem + 2 * BM * BK;

  const int tid = threadIdx.x;
  const int lane = tid & 63;
  const int wv = tid >> 6;
  const int mBase = (wv >> 1) * 64;
  const int nBase = (wv & 1) * 64;
  const int ml = lane & 15;
  const int quad = lane >> 4;
  const int rowBase = blockIdx.x * BM;
  const int colBase = blockIdx.y * BN;

  // staging geometry: wave wv stages tile rows [wv*32, wv*32+32) of A and B.
  const int lrow = lane >> 2;  // 0..15
  const int lslot = lane & 3;  // 16B slot within 64B row

  f32x4 acc[4][4];
  const f32x4 zero = {0.f, 0.f, 0.f, 0.f};
#pragma unroll
  for (int i = 0; i < 4; i++)
#pragma unroll
    for (int j = 0; j < 4; j++) acc[i][j] = zero;

  auto stage = [&](int k0, int buf) {
    const _Float16* Ap;
    int kl, Kp;
    if (k0 < K0) {
      Ap = A0; kl = k0; Kp = K0;
    } else if (k0 < K0 + K1) {
      Ap = A1; kl = k0 - K0; Kp = K1;
    } else {
      Ap = A2; kl = k0 - K0 - K1; Kp = K2;
    }
    char* Ab = (char*)(As0 + buf * BM * BK);
    char* Bb = (char*)(Bs0 + buf * BN * BK);
#pragma unroll
    for (int c = 0; c < 2; c++) {
      int trow = wv * 32 + c * 16 + lrow;       // tile row 0..127
      int sws = lslot ^ (trow & 3);             // swizzled global 16B slot
      size_t ldsoff = (size_t)(wv * 32 + c * 16) * 64;  // bytes, wave-uniform
      int gr = rowBase + trow;
      if (gr > nrows - 1) gr = nrows - 1;       // clamp: garbage rows skipped on store
      gload_lds16(Ap + (size_t)gr * Kp + kl + sws * 8, Ab + ldsoff);
      gload_lds16(Bth + (size_t)(colBase + trow) * Ktot + k0 + sws * 8, Bb + ldsoff);
    }
  };

  const int ntile = Ktot / BK;
  stage(0, 0);
  __syncthreads();
  int cur = 0;
  for (int t = 0; t < ntile; ++t) {
    if (t + 1 < ntile) stage((t + 1) * BK, cur ^ 1);

    f16x8 av[4], bv[4];
#pragma unroll
    for (int nt = 0; nt < 4; nt++) {
      int nrow = nBase + nt * 16 + ml;
      int boff = nrow * 32 + ((quad ^ (nrow & 3)) << 3);
      bv[nt] = *(const f16x8*)&Bs0[cur * BN * BK + boff];
    }
#pragma unroll
    for (int mt = 0; mt < 4; mt++) {
      int mrow = mBase + mt * 16 + ml;
      int aoff = mrow * 32 + ((quad ^ (mrow & 3)) << 3);
      av[mt] = *(const f16x8*)&As0[cur * BM * BK + aoff];
    }
#pragma unroll
    for (int mt = 0; mt < 4; mt++)
#pragma unroll
      for (int nt = 0; nt < 4; nt++) {
        acc[mt][nt] =
            __builtin_amdgcn_mfma_f32_16x16x32_f16(av[mt], bv[nt], acc[mt][nt], 0, 0, 0);
      }
    __syncthreads();
    cur ^= 1;
  }

  // epilogue: C/D layout col=lane&15, row=quad*4+reg
  if (out_half) {
    // stage full 128x128 fp16 tile in smem (staging bufs dead past final barrier)
    _Float16* Ct = smem;
#pragma unroll
    for (int nt = 0; nt < 4; nt++) {
      int colL = nBase + nt * 16 + ml;
      float bv = bias ? bias[colBase + colL] : 0.f;
#pragma unroll
      for (int mt = 0; mt < 4; mt++) {
        int rowL0 = mBase + mt * 16 + quad * 4;
#pragma unroll
        for (int r = 0; r < 4; r++) {
          int rowL = rowL0 + r;
          int grow = rowBase + rowL;
          float v = acc[mt][nt][r];
          if (row_scale) v *= row_scale[grow < nrows ? grow : nrows - 1];
          v += bv;
          if (relu) v = fmaxf(v, 0.f);
          Ct[rowL * 128 + colL] = (_Float16)v;
        }
      }
    }
    __syncthreads();
    // coalesced copy-out: 128 rows x 256B = 2048 x 16B chunks
    for (int idx = tid; idx < 2048; idx += 256) {
      int rowL = idx >> 4;
      int chunk = idx & 15;
      int grow = rowBase + rowL;
      if (grow < nrows) {
        *(uint4*)((_Float16*)Cmat + (size_t)grow * M + colBase + chunk * 8) =
            *(const uint4*)&Ct[rowL * 128 + chunk * 8];
      }
    }
  } else {
#pragma unroll
    for (int nt = 0; nt < 4; nt++) {
      int col = colBase + nBase + nt * 16 + ml;
      float bv = bias ? bias[col] : 0.f;
#pragma unroll
      for (int mt = 0; mt < 4; mt++) {
        int row0 = rowBase + mBase + mt * 16 + quad * 4;
#pragma unroll
        for (int r = 0; r < 4; r++) {
          int grow = row0 + r;
          if (grow >= nrows) continue;
          float v = acc[mt][nt][r];
          if (row_scale) v *= row_scale[grow];
          v += bv;
          if (relu) v = fmaxf(v, 0.f);
          ((float*)Cmat)[(size_t)grow * M + col] = v;
        }
      }
    }
  }
}

// ---------------------------------------------------------------- launch

extern "C" void kernel_launch(void* const* d_in, const int* in_sizes, int n_in, void* d_out,
                              int out_size, void* d_ws, size_t ws_size, hipStream_t stream) {
  const float* x_self     = (const float*)d_in[0];
  const float* x_neighbor = (const float*)d_in[1];
  const void*  edge_index = d_in[2];
  const float* W_in_self  = (const float*)d_in[3];
  const float* b_in_self  = (const float*)d_in[4];
  const float* W_out_self = (const float*)d_in[5];
  const float* b_out_self = (const float*)d_in[6];
  const float* Wg1        = (const float*)d_in[7];
  const float* bg1        = (const float*)d_in[8];
  const float* Wg2        = (const float*)d_in[9];
  const float* bg2        = (const float*)d_in[10];
  const float* W_out      = (const float*)d_in[11];
  const float* b_out      = (const float*)d_in[12];
  float* out = (float*)d_out;

  char* ws = (char*)d_ws;
  size_t off = 0;
  auto alloc = [&](size_t bytes) -> void* {
    void* p = ws + off;
    off = (off + bytes + 255) & ~(size_t)255;
    return p;
  };
  int* counts = (int*)alloc((size_t)2 * NNODES * 4 + 2048);  // counts+fillc+gcount+novf
  int* fillc  = counts + NNODES;
  int* gcount = counts + 2 * NNODES;         // NBUCK ints
  int* novf   = gcount + NBUCK;              // 1 int (within the 512-int pad)
  int*   offs   = (int*)alloc((size_t)(NNODES + 1) * 4);
  int*   csr    = (int*)alloc((size_t)NEDGES * 4);
  int*   bsums  = (int*)alloc(4096);
  int*   flag   = (int*)alloc(256);
  float* dinv   = (float*)alloc((size_t)NNODES * 4);
  _Float16* wt1 = (_Float16*)alloc(32768 * 2);  // W_in_self  K=128 M=256
  _Float16* wt2 = (_Float16*)alloc(49152 * 2);  // W_out_self K=384 M=128
  _Float16* wt3 = (_Float16*)alloc(32768 * 2);  // Wg1        K=128 M=256
  _Float16* wt4 = (_Float16*)alloc(32768 * 2);  // Wg2        K=256 M=128
  _Float16* wt5 = (_Float16*)alloc(65536 * 2);  // W_out      K=512 M=128
  float* bufA = (float*)alloc((size_t)NNODES * 256 * 4);
  float* bufB = (float*)alloc((size_t)NNODES * 256 * 4);
  (void)ws_size;

  // bpairs (12.8 MB, packed u32) aliases bufA: dead before GEMM-1 writes l1 there.
  // ovf (12.8 MB) aliases bufB base: dead before xcvt2 writes ybuf there.
  unsigned int* bpairs = (unsigned int*)bufA;
  unsigned long long* ovf = (unsigned long long*)bufB;

  const int nb = (NNODES + SCAN_TILE - 1) / SCAN_TILE;  // 98
  const int gridRows = (NNODES + BM - 1) / BM;          // 782

  detect_kernel<<<1, 64, 0, stream>>>((const unsigned int*)edge_index, flag);
  zero_int_kernel<<<(2 * NNODES + 512 + 255) / 256, 256, 0, stream>>>(counts,
                                                                      2 * NNODES + 512);
  bucket_kernel<<<256, 1024, 0, stream>>>(edge_index, flag, counts, gcount, bpairs, ovf, novf);
  dinv_kernel<<<(NNODES + 255) / 256, 256, 0, stream>>>(counts, dinv);
  scan_reduce_kernel<<<nb, SCAN_B, 0, stream>>>(counts, bsums);
  scan_bsums_kernel<<<1, 64, 0, stream>>>(bsums, offs, nb);
  scan_write_kernel<<<nb, SCAN_B, 0, stream>>>(counts, bsums, offs);
  ovf_scatter_kernel<<<64, 256, 0, stream>>>(ovf, novf, offs, fillc, csr);
  fillwin_kernel<<<NBUCK, 256, 0, stream>>>(bpairs, gcount, offs, fillc, csr);

  wprep_f16_kernel<<<(32768 + 255) / 256, 256, 0, stream>>>(W_in_self, 128, 256, wt1);
  wprep_f16_kernel<<<(49152 + 255) / 256, 256, 0, stream>>>(W_out_self, 384, 128, wt2);
  wprep_f16_kernel<<<(32768 + 255) / 256, 256, 0, stream>>>(Wg1, 128, 256, wt3);
  wprep_f16_kernel<<<(32768 + 255) / 256, 256, 0, stream>>>(Wg2, 256, 128, wt4);
  wprep_f16_kernel<<<(65536 + 255) / 256, 256, 0, stream>>>(W_out, 512, 128, wt5);

  // ---- fp16 copies of the fp32 inputs (in bufB's permanently-free top half) ----
  _Float16* xs16 = (_Float16*)(bufB + (size_t)NNODES * 128);
  _Float16* xn16 = xs16 + (size_t)NNODES * 128;
  _Float16* ybuf = (_Float16*)bufB;  // dinv-scaled x_neighbor (overwrites dead ovf)
  xcvt_kernel<<<(NNODES * 32 + 255) / 256, 256, 0, stream>>>(x_self, (f16x4*)xs16, NNODES * 32);
  xcvt2_kernel<<<(NNODES * 32 + 255) / 256, 256, 0, stream>>>(x_neighbor, dinv, (f16x4*)xn16,
                                                              (f16x4*)ybuf);

  // ---- dense self branch ----
  // l1 = relu(xs16 @ W1 + b1) stored fp16 [N,256] in bufA (bpairs dead by now)
  _Float16* l1 = (_Float16*)bufA;
  gemm_f16_kernel<<<dim3(gridRows, 2), 256, 0, stream>>>(
      xs16, 128, nullptr, 0, nullptr, 0, wt1, 128, 256, b_in_self, nullptr, l1, 1, 1, NNODES);
  gemm_f16_kernel<<<dim3(gridRows, 1), 256, 0, stream>>>(
      xs16, 128, l1, 256, nullptr, 0, wt2, 384, 128, b_out_self, nullptr, out, 0, 0, NNODES);

  // ---- GCN branch (A_norm @ (X W) == (A_norm @ X) W), all intermediates fp16 ----
  _Float16* aggx = (_Float16*)bufA;
  _Float16* g1   = (_Float16*)bufB;
  _Float16* xw2  = (_Float16*)bufA;
  _Float16* g2   = (_Float16*)bufA + (size_t)NNODES * 128;

  aggregate_half_kernel<<<NNODES / 4, 256, 0, stream>>>((const f16x2*)ybuf, aggx, 1, offs, csr,
                                                        dinv, nullptr);
  gemm_f16_kernel<<<dim3(gridRows, 2), 256, 0, stream>>>(
      aggx, 128, nullptr, 0, nullptr, 0, wt3, 128, 256, bg1, nullptr, g1, 0, 1, NNODES);
  // xw2 = (fp16)((g1 @ Wg2) * dinv[row])  (pre-scale for agg2 folded into epilogue)
  gemm_f16_kernel<<<dim3(gridRows, 1), 256, 0, stream>>>(
      g1, 256, nullptr, 0, nullptr, 0, wt4, 256, 128, nullptr, dinv, xw2, 0, 1, NNODES);
  aggregate_half_kernel<<<NNODES / 4, 256, 0, stream>>>((const f16x2*)xw2, g2, 1, offs, csr,
                                                        dinv, bg2);
  gemm_f16_kernel<<<dim3(gridRows, 1), 256, 0, stream>>>(
      xn16, 128, g1, 256, g2, 128, wt5, 512, 128, b_out, nullptr,
      out + (size_t)NNODES * 128, 0, 0, NNODES);
}

// Round 15
// 636.482 us; speedup vs baseline: 1.0953x; 1.0166x over previous
//
#include <hip/hip_runtime.h>
#include <cstdint>
#include <cstddef>

#define NNODES 100000
#define NEDGES 1600000
// D = 128, C = 128 (hard-coded below)

typedef float f32x4 __attribute__((ext_vector_type(4)));
typedef unsigned int u32;
// native fp16 (no hip_fp16.h dependency — clang _Float16)
typedef _Float16 f16x2 __attribute__((ext_vector_type(2)));
typedef _Float16 f16x4 __attribute__((ext_vector_type(4)));
typedef _Float16 f16x8 __attribute__((ext_vector_type(8)));

// async global->LDS, 16B per lane: dest = lds_base + lane*16 (linear), src per-lane.
__device__ __forceinline__ void gload_lds16(const void* g, void* l) {
  __builtin_amdgcn_global_load_lds((const __attribute__((address_space(1))) u32*)g,
                                   (__attribute__((address_space(3))) u32*)l, 16, 0, 0);
}

// ---------------------------------------------------------------- utilities

__global__ void zero_int_kernel(int* __restrict__ p, int n) {
  int i = blockIdx.x * blockDim.x + threadIdx.x;
  if (i < n) p[i] = 0;
}

// int64 vs int32 edge_index detection (high words all zero => int64)
__global__ void detect_kernel(const unsigned int* __restrict__ ei, int* __restrict__ flag) {
  unsigned int v = ei[2 * threadIdx.x + 1];
  unsigned long long b = __ballot(v != 0u);
  if (threadIdx.x == 0) *flag = (b == 0ull) ? 1 : 0;
}

__device__ __forceinline__ int edge_val(const void* ei, int is64, long long idx) {
  if (is64) return (int)((const long long*)ei)[idx];
  return ((const int*)ei)[idx];
}

// ---------------------------------------------------------------- degree

__global__ void dinv_kernel(const int* __restrict__ counts, float* __restrict__ dinv) {
  int i = blockIdx.x * blockDim.x + threadIdx.x;
  if (i < NNODES) dinv[i] = rsqrtf((float)(counts[i] + 1));  // +1 self loop
}

#define SCAN_B 256
#define SCAN_TILE 1024

__global__ void scan_reduce_kernel(const int* __restrict__ counts, int* __restrict__ bsums) {
  __shared__ int sd[SCAN_B];
  int t = threadIdx.x;
  int base = blockIdx.x * SCAN_TILE + t * 4;
  int s = 0;
#pragma unroll
  for (int i = 0; i < 4; i++) {
    int idx = base + i;
    if (idx < NNODES) s += counts[idx];
  }
  sd[t] = s;
  __syncthreads();
  for (int o = SCAN_B / 2; o > 0; o >>= 1) {
    if (t < o) sd[t] += sd[t + o];
    __syncthreads();
  }
  if (t == 0) bsums[blockIdx.x] = sd[0];
}

__global__ void scan_bsums_kernel(int* __restrict__ bsums, int* __restrict__ offs, int nb) {
  if (threadIdx.x == 0 && blockIdx.x == 0) {
    int run = 0;
    for (int b = 0; b < nb; b++) {
      int v = bsums[b];
      bsums[b] = run;
      run += v;
    }
    offs[NNODES] = run;
  }
}

__global__ void scan_write_kernel(const int* __restrict__ counts, const int* __restrict__ bsums,
                                  int* __restrict__ offs) {
  __shared__ int sd[SCAN_B];
  int t = threadIdx.x;
  int base = blockIdx.x * SCAN_TILE + t * 4;
  int v[4];
  int s = 0;
#pragma unroll
  for (int i = 0; i < 4; i++) {
    int idx = base + i;
    v[i] = (idx < NNODES) ? counts[idx] : 0;
    s += v[i];
  }
  sd[t] = s;
  __syncthreads();
  for (int o = 1; o < SCAN_B; o <<= 1) {
    int x = (t >= o) ? sd[t - o] : 0;
    __syncthreads();
    sd[t] += x;
    __syncthreads();
  }
  int run = sd[t] - s + bsums[blockIdx.x];
#pragma unroll
  for (int i = 0; i < 4; i++) {
    int idx = base + i;
    if (idx < NNODES) {
      offs[idx] = run;
      run += v[i];
    }
  }
}

// ---------------------------------------------------------------- bucketed CSR fill
// Pass A (bucket_kernel): partition edges into 391 dst-buckets of 256 nodes each,
//   AND histogram global degree counts. 256 blocks x 1024 threads.
//   r14 PMC lesson: scattered-write cost = dirty SECTORS x 64B (59 MB for 6.4 MB
//   payload) — per-(block,bucket) runs were written by different waves over time,
//   dirtying each sector repeatedly. Fix: STAGE the block's whole 6250-pair chunk
//   in LDS grouped by bucket (local scan gives per-bucket bases), then FLUSH with
//   consecutive threads writing consecutive addresses — each ~64B run produced by
//   one store burst, written once. Scattered global stores -> LDS scatters (free).
// Pass B (fillwin_kernel): block b owns csr window [offs[b*256], offs[(b+1)*256));
//   scatter inside LDS, write back fully coalesced.

#define BK_SHIFT 8
#define NBUCK 391   // ceil(NNODES / 256)
#define BCAP 8192   // pairs per bucket (mean 4096, +64 sigma)
#define WCAP 12288  // csr window ints in LDS (mean 4096, +128 sigma)
#define ECHUNK 6250 // NEDGES / 256

__global__ __launch_bounds__(1024) void bucket_kernel(
    const void* __restrict__ ei, const int* __restrict__ flag, int* __restrict__ counts,
    int* __restrict__ gcount, unsigned int* __restrict__ bpairs,
    unsigned long long* __restrict__ ovf, int* __restrict__ novf) {
  __shared__ unsigned int lpairs[ECHUNK];      // 25.0 KB pair staging
  __shared__ unsigned short lbkt[ECHUNK];      // 12.5 KB bucket id per slot
  __shared__ int lcount[512];                  // padded for scan
  __shared__ int lscan[512];                   // inclusive scan
  __shared__ int gbase[NBUCK];
  __shared__ int lcur[NBUCK];
  const int is64 = *flag;
  const long long e0 = (long long)blockIdx.x * ECHUNK;
  const int t = threadIdx.x;

  for (int i = t; i < 512; i += 1024) lcount[i] = 0;
  for (int i = t; i < NBUCK; i += 1024) lcur[i] = 0;
  __syncthreads();
  // pass 1: per-bucket counts + global degree histogram
  for (int e = t; e < ECHUNK; e += 1024) {
    int d = edge_val(ei, is64, NEDGES + e0 + e);
    atomicAdd(&lcount[d >> BK_SHIFT], 1);
    atomicAdd(&counts[d], 1);
  }
  __syncthreads();
  // inclusive Hillis-Steele scan over 512 (NBUCK padded with zeros)
  if (t < 512) lscan[t] = lcount[t];
  __syncthreads();
  for (int o = 1; o < 512; o <<= 1) {
    int x = 0;
    if (t < 512 && t >= o) x = lscan[t - o];
    __syncthreads();
    if (t < 512) lscan[t] += x;
    __syncthreads();
  }
  // one global reservation per (block,bucket)
  for (int i = t; i < NBUCK; i += 1024) {
    int c = lcount[i];
    gbase[i] = c ? atomicAdd(&gcount[i], c) : 0;
  }
  __syncthreads();
  // pass 2: stage pairs into LDS grouped by bucket
  for (int e = t; e < ECHUNK; e += 1024) {
    int s = edge_val(ei, is64, e0 + e);
    int d = edge_val(ei, is64, NEDGES + e0 + e);
    int b = d >> BK_SHIFT;
    int pos = (lscan[b] - lcount[b]) + atomicAdd(&lcur[b], 1);
    lpairs[pos] = ((unsigned)(d & 255) << 24) | (unsigned)s;  // s < 2^24
    lbkt[pos] = (unsigned short)b;
  }
  __syncthreads();
  // flush: consecutive threads -> consecutive addresses within each bucket run
  for (int i = t; i < ECHUNK; i += 1024) {
    int b = lbkt[i];
    int rank = i - (lscan[b] - lcount[b]);
    int gpos = gbase[b] + rank;
    unsigned int pr = lpairs[i];
    if (gpos < BCAP) {
      bpairs[(size_t)b * BCAP + gpos] = pr;
    } else {
      // bucket overflow: append to u64 ovf list (capacity NEDGES — always fits)
      int o = atomicAdd(novf, 1);
      int d = (b << BK_SHIFT) | (int)(pr >> 24);
      ovf[o] = ((unsigned long long)(unsigned)d << 32) | (pr & 0xffffffu);
    }
  }
}

// drain overflow pairs (novf == 0 for Poisson(16) input — exits immediately)
__global__ void ovf_scatter_kernel(const unsigned long long* __restrict__ ovf,
                                   const int* __restrict__ novf, const int* __restrict__ offs,
                                   int* __restrict__ fillc, int* __restrict__ csr) {
  int n = *novf;
  for (int i = blockIdx.x * blockDim.x + threadIdx.x; i < n;
       i += gridDim.x * blockDim.x) {
    unsigned long long v = ovf[i];
    int d = (int)(v >> 32);
    int s = (int)(v & 0xffffffffull);
    int p = offs[d] + atomicAdd(&fillc[d], 1);
    csr[p] = s;
  }
}

__global__ __launch_bounds__(256) void fillwin_kernel(
    const unsigned int* __restrict__ bpairs, const int* __restrict__ gcount,
    const int* __restrict__ offs, int* __restrict__ fillc, int* __restrict__ csr) {
  __shared__ int win[WCAP];
  __shared__ int nfill[256];
  const int b = blockIdx.x;
  const int nlo = b << BK_SHIFT;
  const int nhi = min(nlo + 256, NNODES);
  const int base = offs[nlo];
  const int W = offs[nhi] - base;
  int cnt = gcount[b];
  if (cnt > BCAP) cnt = BCAP;
  if (W <= WCAP) {
    if ((int)threadIdx.x < nhi - nlo) nfill[threadIdx.x] = fillc[nlo + threadIdx.x];
    // preserve any ovf-scattered cells
    for (int i = threadIdx.x; i < W; i += 256) win[i] = csr[base + i];
    __syncthreads();
    for (int i = threadIdx.x; i < cnt; i += 256) {
      unsigned int v = bpairs[(size_t)b * BCAP + i];
      int dl = (int)(v >> 24);          // d - nlo
      int s = (int)(v & 0xffffffu);
      int p = offs[nlo + dl] - base + atomicAdd(&nfill[dl], 1);
      win[p] = s;
    }
    __syncthreads();
    for (int i = threadIdx.x; i < W; i += 256) csr[base + i] = win[i];
  } else {
    // window overflow: direct scatter (continues fillc from ovf_scatter)
    for (int i = threadIdx.x; i < cnt; i += 256) {
      unsigned int v = bpairs[(size_t)b * BCAP + i];
      int dl = (int)(v >> 24);
      int s = (int)(v & 0xffffffu);
      int d = nlo + dl;
      int p = offs[d] + atomicAdd(&fillc[d], 1);
      csr[p] = s;
    }
  }
}

// ---------------------------------------------------------------- fp32 -> fp16 convert

__global__ void xcvt_kernel(const float* __restrict__ x, f16x4* __restrict__ y, int n4) {
  int i = blockIdx.x * blockDim.x + threadIdx.x;
  if (i >= n4) return;
  float4 v = ((const float4*)x)[i];
  f16x4 h;
  h[0] = (_Float16)v.x;
  h[1] = (_Float16)v.y;
  h[2] = (_Float16)v.z;
  h[3] = (_Float16)v.w;
  y[i] = h;
}

// fused convert + prescale: one pass over x_neighbor produces xn16 (unscaled)
// and ybuf (dinv-scaled) — saves prescale16's separate 51 MB pass.
__global__ void xcvt2_kernel(const float* __restrict__ x, const float* __restrict__ dinv,
                             f16x4* __restrict__ xn, f16x4* __restrict__ yb) {
  int i = blockIdx.x * blockDim.x + threadIdx.x;  // over NNODES*32 float4
  if (i >= NNODES * 32) return;
  int row = i >> 5;
  float s = dinv[row];
  float4 v = ((const float4*)x)[i];
  f16x4 h, hp;
  h[0] = (_Float16)v.x;
  h[1] = (_Float16)v.y;
  h[2] = (_Float16)v.z;
  h[3] = (_Float16)v.w;
  hp[0] = (_Float16)(v.x * s);
  hp[1] = (_Float16)(v.y * s);
  hp[2] = (_Float16)(v.z * s);
  hp[3] = (_Float16)(v.w * s);
  xn[i] = h;
  yb[i] = hp;
}

// ---------------------------------------------------------------- aggregation (gather, fp16 in)
// r10 form (r11's 16B/lane restructure regressed 68->88us: gather is MLP-bound —
// 8 full-wave loads in flight beats 4 wide loads; 16B/lane tail crawled for
// deg<16 nodes).
// Input rows are PRE-SCALED fp16: y_j = (fp16)(dinv[j]*x_j).   256 B/row.
// out[i,:] = dinv[i] * (y_i + sum_{j in nbr(i)} y_j) + bias   (fp32 accumulate)
// One wave per node, f16x2 per lane, 8-way unrolled gathers (4 fp32 accumulators).

__device__ __forceinline__ float2 f16x2_to_f32(f16x2 h) {
  return make_float2((float)h[0], (float)h[1]);
}

__global__ __launch_bounds__(256) void aggregate_half_kernel(
    const f16x2* __restrict__ in, void* __restrict__ out, int out_half,
    const int* __restrict__ offs, const int* __restrict__ csr, const float* __restrict__ dinv,
    const float* __restrict__ bias) {
  int node = blockIdx.x * 4 + (threadIdx.x >> 6);
  if (node >= NNODES) return;
  int ch = threadIdx.x & 63;  // f16x2 index within row (64 x f16x2 = 128 cols)
  int beg = offs[node], end = offs[node + 1];

  // self term (pre-scaled row)
  float2 a0 = f16x2_to_f32(in[(size_t)node * 64 + ch]);
  float2 a1 = make_float2(0.f, 0.f);
  float2 a2 = make_float2(0.f, 0.f);
  float2 a3 = make_float2(0.f, 0.f);

  int p = beg;
  for (; p + 8 <= end; p += 8) {
    int j0 = csr[p + 0], j1 = csr[p + 1], j2 = csr[p + 2], j3 = csr[p + 3];
    int j4 = csr[p + 4], j5 = csr[p + 5], j6 = csr[p + 6], j7 = csr[p + 7];
    f16x2 h0 = in[(size_t)j0 * 64 + ch];
    f16x2 h1 = in[(size_t)j1 * 64 + ch];
    f16x2 h2 = in[(size_t)j2 * 64 + ch];
    f16x2 h3 = in[(size_t)j3 * 64 + ch];
    f16x2 h4 = in[(size_t)j4 * 64 + ch];
    f16x2 h5 = in[(size_t)j5 * 64 + ch];
    f16x2 h6 = in[(size_t)j6 * 64 + ch];
    f16x2 h7 = in[(size_t)j7 * 64 + ch];
    float2 v0 = f16x2_to_f32(h0);
    float2 v1 = f16x2_to_f32(h1);
    float2 v2 = f16x2_to_f32(h2);
    float2 v3 = f16x2_to_f32(h3);
    float2 v4 = f16x2_to_f32(h4);
    float2 v5 = f16x2_to_f32(h5);
    float2 v6 = f16x2_to_f32(h6);
    float2 v7 = f16x2_to_f32(h7);
    a0.x += v0.x; a0.y += v0.y;
    a1.x += v1.x; a1.y += v1.y;
    a2.x += v2.x; a2.y += v2.y;
    a3.x += v3.x; a3.y += v3.y;
    a0.x += v4.x; a0.y += v4.y;
    a1.x += v5.x; a1.y += v5.y;
    a2.x += v6.x; a2.y += v6.y;
    a3.x += v7.x; a3.y += v7.y;
  }
  for (; p + 2 <= end; p += 2) {
    int j0 = csr[p], j1 = csr[p + 1];
    float2 v0 = f16x2_to_f32(in[(size_t)j0 * 64 + ch]);
    float2 v1 = f16x2_to_f32(in[(size_t)j1 * 64 + ch]);
    a0.x += v0.x; a0.y += v0.y;
    a1.x += v1.x; a1.y += v1.y;
  }
  if (p < end) {
    float2 v0 = f16x2_to_f32(in[(size_t)csr[p] * 64 + ch]);
    a0.x += v0.x; a0.y += v0.y;
  }

  float di = dinv[node];
  int c = ch * 2;
  float2 r;
  r.x = di * (a0.x + a1.x + a2.x + a3.x);
  r.y = di * (a0.y + a1.y + a2.y + a3.y);
  if (bias) {
    r.x += bias[c];
    r.y += bias[c + 1];
  }
  if (out_half) {
    f16x2 h;
    h[0] = (_Float16)r.x;
    h[1] = (_Float16)r.y;
    ((f16x2*)out)[(size_t)node * 64 + ch] = h;
  } else {
    *(float2*)((float*)out + (size_t)node * 128 + c) = r;
  }
}

// ---------------------------------------------------------------- weight prep
// W [K][M] fp32  ->  Wt [M][K] fp16 (transposed).  Single fp16 — wl dropped:
// A is already fp16 (2^-11), wl only polished the smaller error source.

__global__ void wprep_f16_kernel(const float* __restrict__ W, int K, int M,
                                 _Float16* __restrict__ th) {
  int i = blockIdx.x * blockDim.x + threadIdx.x;
  if (i >= K * M) return;
  int k = i / M, m = i - k * M;
  th[(size_t)m * K + k] = (_Float16)W[i];
}

// ---------------------------------------------------------------- fp16 MFMA GEMM
// C[n,M] = concat(A0,A1,A2) @ W (+row_scale)(+bias)(+relu).  All fp16 operands,
// fp32 accumulate, 1 MFMA per tile per K-step.
// 2-PHASE DOUBLE-BUFFERED staging; LDS 32 KB (one smem block: As[2] | Bs[2]).
// EPILOGUE (out_half): LDS-staged coalesced writes (r9 PMC: direct 32B fp16 runs
// caused 2.15x sector amplification; staging removed it, r10 confirmed -62us).

#define BM 128
#define BN 128
#define BK 32

__global__ __launch_bounds__(256) void gemm_f16_kernel(
    const _Float16* __restrict__ A0, int K0, const _Float16* __restrict__ A1, int K1,
    const _Float16* __restrict__ A2, int K2, const _Float16* __restrict__ Bth, int Ktot, int M,
    const float* __restrict__ bias, const float* __restrict__ row_scale,
    void* __restrict__ Cmat, int relu, int out_half, int nrows) {
  __shared__ _Float16 smem[4 * BM * BK];  // 32 KB: As[2] | Bs[2]; reused as C-tile
  _Float16* const As0 = smem;
  _Float16* const Bs0 = smem + 2 * BM * BK;

  const int tid = threadIdx.x;
  const int lane = tid & 63;
  const int wv = tid >> 6;
  const int mBase = (wv >> 1) * 64;
  const int nBase = (wv & 1) * 64;
  const int ml = lane & 15;
  const int quad = lane >> 4;
  const int rowBase = blockIdx.x * BM;
  const int colBase = blockIdx.y * BN;

  // staging geometry: wave wv stages tile rows [wv*32, wv*32+32) of A and B.
  const int lrow = lane >> 2;  // 0..15
  const int lslot = lane & 3;  // 16B slot within 64B row

  f32x4 acc[4][4];
  const f32x4 zero = {0.f, 0.f, 0.f, 0.f};
#pragma unroll
  for (int i = 0; i < 4; i++)
#pragma unroll
    for (int j = 0; j < 4; j++) acc[i][j] = zero;

  auto stage = [&](int k0, int buf) {
    const _Float16* Ap;
    int kl, Kp;
    if (k0 < K0) {
      Ap = A0; kl = k0; Kp = K0;
    } else if (k0 < K0 + K1) {
      Ap = A1; kl = k0 - K0; Kp = K1;
    } else {
      Ap = A2; kl = k0 - K0 - K1; Kp = K2;
    }
    char* Ab = (char*)(As0 + buf * BM * BK);
    char* Bb = (char*)(Bs0 + buf * BN * BK);
#pragma unroll
    for (int c = 0; c < 2; c++) {
      int trow = wv * 32 + c * 16 + lrow;       // tile row 0..127
      int sws = lslot ^ (trow & 3);             // swizzled global 16B slot
      size_t ldsoff = (size_t)(wv * 32 + c * 16) * 64;  // bytes, wave-uniform
      int gr = rowBase + trow;
      if (gr > nrows - 1) gr = nrows - 1;       // clamp: garbage rows skipped on store
      gload_lds16(Ap + (size_t)gr * Kp + kl + sws * 8, Ab + ldsoff);
      gload_lds16(Bth + (size_t)(colBase + trow) * Ktot + k0 + sws * 8, Bb + ldsoff);
    }
  };

  const int ntile = Ktot / BK;
  stage(0, 0);
  __syncthreads();
  int cur = 0;
  for (int t = 0; t < ntile; ++t) {
    if (t + 1 < ntile) stage((t + 1) * BK, cur ^ 1);

    f16x8 av[4], bv[4];
#pragma unroll
    for (int nt = 0; nt < 4; nt++) {
      int nrow = nBase + nt * 16 + ml;
      int boff = nrow * 32 + ((quad ^ (nrow & 3)) << 3);
      bv[nt] = *(const f16x8*)&Bs0[cur * BN * BK + boff];
    }
#pragma unroll
    for (int mt = 0; mt < 4; mt++) {
      int mrow = mBase + mt * 16 + ml;
      int aoff = mrow * 32 + ((quad ^ (mrow & 3)) << 3);
      av[mt] = *(const f16x8*)&As0[cur * BM * BK + aoff];
    }
#pragma unroll
    for (int mt = 0; mt < 4; mt++)
#pragma unroll
      for (int nt = 0; nt < 4; nt++) {
        acc[mt][nt] =
            __builtin_amdgcn_mfma_f32_16x16x32_f16(av[mt], bv[nt], acc[mt][nt], 0, 0, 0);
      }
    __syncthreads();
    cur ^= 1;
  }

  // epilogue: C/D layout col=lane&15, row=quad*4+reg
  if (out_half) {
    // stage full 128x128 fp16 tile in smem (staging bufs dead past final barrier)
    _Float16* Ct = smem;
#pragma unroll
    for (int nt = 0; nt < 4; nt++) {
      int colL = nBase + nt * 16 + ml;
      float bv = bias ? bias[colBase + colL] : 0.f;
#pragma unroll
      for (int mt = 0; mt < 4; mt++) {
        int rowL0 = mBase + mt * 16 + quad * 4;
#pragma unroll
        for (int r = 0; r < 4; r++) {
          int rowL = rowL0 + r;
          int grow = rowBase + rowL;
          float v = acc[mt][nt][r];
          if (row_scale) v *= row_scale[grow < nrows ? grow : nrows - 1];
          v += bv;
          if (relu) v = fmaxf(v, 0.f);
          Ct[rowL * 128 + colL] = (_Float16)v;
        }
      }
    }
    __syncthreads();
    // coalesced copy-out: 128 rows x 256B = 2048 x 16B chunks
    for (int idx = tid; idx < 2048; idx += 256) {
      int rowL = idx >> 4;
      int chunk = idx & 15;
      int grow = rowBase + rowL;
      if (grow < nrows) {
        *(uint4*)((_Float16*)Cmat + (size_t)grow * M + colBase + chunk * 8) =
            *(const uint4*)&Ct[rowL * 128 + chunk * 8];
      }
    }
  } else {
#pragma unroll
    for (int nt = 0; nt < 4; nt++) {
      int col = colBase + nBase + nt * 16 + ml;
      float bv = bias ? bias[col] : 0.f;
#pragma unroll
      for (int mt = 0; mt < 4; mt++) {
        int row0 = rowBase + mBase + mt * 16 + quad * 4;
#pragma unroll
        for (int r = 0; r < 4; r++) {
          int grow = row0 + r;
          if (grow >= nrows) continue;
          float v = acc[mt][nt][r];
          if (row_scale) v *= row_scale[grow];
          v += bv;
          if (relu) v = fmaxf(v, 0.f);
          ((float*)Cmat)[(size_t)grow * M + col] = v;
        }
      }
    }
  }
}

// ---------------------------------------------------------------- launch

extern "C" void kernel_launch(void* const* d_in, const int* in_sizes, int n_in, void* d_out,
                              int out_size, void* d_ws, size_t ws_size, hipStream_t stream) {
  const float* x_self     = (const float*)d_in[0];
  const float* x_neighbor = (const float*)d_in[1];
  const void*  edge_index = d_in[2];
  const float* W_in_self  = (const float*)d_in[3];
  const float* b_in_self  = (const float*)d_in[4];
  const float* W_out_self = (const float*)d_in[5];
  const float* b_out_self = (const float*)d_in[6];
  const float* Wg1        = (const float*)d_in[7];
  const float* bg1        = (const float*)d_in[8];
  const float* Wg2        = (const float*)d_in[9];
  const float* bg2        = (const float*)d_in[10];
  const float* W_out      = (const float*)d_in[11];
  const float* b_out      = (const float*)d_in[12];
  float* out = (float*)d_out;

  char* ws = (char*)d_ws;
  size_t off = 0;
  auto alloc = [&](size_t bytes) -> void* {
    void* p = ws + off;
    off = (off + bytes + 255) & ~(size_t)255;
    return p;
  };
  int* counts = (int*)alloc((size_t)2 * NNODES * 4 + 2048);  // counts+fillc+gcount+novf
  int* fillc  = counts + NNODES;
  int* gcount = counts + 2 * NNODES;         // NBUCK ints
  int* novf   = gcount + NBUCK;              // 1 int (within the 512-int pad)
  int*   offs   = (int*)alloc((size_t)(NNODES + 1) * 4);
  int*   csr    = (int*)alloc((size_t)NEDGES * 4);
  int*   bsums  = (int*)alloc(4096);
  int*   flag   = (int*)alloc(256);
  float* dinv   = (float*)alloc((size_t)NNODES * 4);
  _Float16* wt1 = (_Float16*)alloc(32768 * 2);  // W_in_self  K=128 M=256
  _Float16* wt2 = (_Float16*)alloc(49152 * 2);  // W_out_self K=384 M=128
  _Float16* wt3 = (_Float16*)alloc(32768 * 2);  // Wg1        K=128 M=256
  _Float16* wt4 = (_Float16*)alloc(32768 * 2);  // Wg2        K=256 M=128
  _Float16* wt5 = (_Float16*)alloc(65536 * 2);  // W_out      K=512 M=128
  float* bufA = (float*)alloc((size_t)NNODES * 256 * 4);
  float* bufB = (float*)alloc((size_t)NNODES * 256 * 4);
  (void)ws_size;

  // bpairs (12.8 MB, packed u32) aliases bufA: dead before GEMM-1 writes l1 there.
  // ovf (12.8 MB) aliases bufB base: dead before xcvt2 writes ybuf there.
  unsigned int* bpairs = (unsigned int*)bufA;
  unsigned long long* ovf = (unsigned long long*)bufB;

  const int nb = (NNODES + SCAN_TILE - 1) / SCAN_TILE;  // 98
  const int gridRows = (NNODES + BM - 1) / BM;          // 782

  detect_kernel<<<1, 64, 0, stream>>>((const unsigned int*)edge_index, flag);
  zero_int_kernel<<<(2 * NNODES + 512 + 255) / 256, 256, 0, stream>>>(counts,
                                                                      2 * NNODES + 512);
  bucket_kernel<<<256, 1024, 0, stream>>>(edge_index, flag, counts, gcount, bpairs, ovf, novf);
  dinv_kernel<<<(NNODES + 255) / 256, 256, 0, stream>>>(counts, dinv);
  scan_reduce_kernel<<<nb, SCAN_B, 0, stream>>>(counts, bsums);
  scan_bsums_kernel<<<1, 64, 0, stream>>>(bsums, offs, nb);
  scan_write_kernel<<<nb, SCAN_B, 0, stream>>>(counts, bsums, offs);
  ovf_scatter_kernel<<<64, 256, 0, stream>>>(ovf, novf, offs, fillc, csr);
  fillwin_kernel<<<NBUCK, 256, 0, stream>>>(bpairs, gcount, offs, fillc, csr);

  wprep_f16_kernel<<<(32768 + 255) / 256, 256, 0, stream>>>(W_in_self, 128, 256, wt1);
  wprep_f16_kernel<<<(49152 + 255) / 256, 256, 0, stream>>>(W_out_self, 384, 128, wt2);
  wprep_f16_kernel<<<(32768 + 255) / 256, 256, 0, stream>>>(Wg1, 128, 256, wt3);
  wprep_f16_kernel<<<(32768 + 255) / 256, 256, 0, stream>>>(Wg2, 256, 128, wt4);
  wprep_f16_kernel<<<(65536 + 255) / 256, 256, 0, stream>>>(W_out, 512, 128, wt5);

  // ---- fp16 copies of the fp32 inputs (in bufB's permanently-free top half) ----
  _Float16* xs16 = (_Float16*)(bufB + (size_t)NNODES * 128);
  _Float16* xn16 = xs16 + (size_t)NNODES * 128;
  _Float16* ybuf = (_Float16*)bufB;  // dinv-scaled x_neighbor (overwrites dead ovf)
  xcvt_kernel<<<(NNODES * 32 + 255) / 256, 256, 0, stream>>>(x_self, (f16x4*)xs16, NNODES * 32);
  xcvt2_kernel<<<(NNODES * 32 + 255) / 256, 256, 0, stream>>>(x_neighbor, dinv, (f16x4*)xn16,
                                                              (f16x4*)ybuf);

  // ---- dense self branch ----
  // l1 = relu(xs16 @ W1 + b1) stored fp16 [N,256] in bufA (bpairs dead by now)
  _Float16* l1 = (_Float16*)bufA;
  gemm_f16_kernel<<<dim3(gridRows, 2), 256, 0, stream>>>(
      xs16, 128, nullptr, 0, nullptr, 0, wt1, 128, 256, b_in_self, nullptr, l1, 1, 1, NNODES);
  gemm_f16_kernel<<<dim3(gridRows, 1), 256, 0, stream>>>(
      xs16, 128, l1, 256, nullptr, 0, wt2, 384, 128, b_out_self, nullptr, out, 0, 0, NNODES);

  // ---- GCN branch (A_norm @ (X W) == (A_norm @ X) W), all intermediates fp16 ----
  _Float16* aggx = (_Float16*)bufA;
  _Float16* g1   = (_Float16*)bufB;
  _Float16* xw2  = (_Float16*)bufA;
  _Float16* g2   = (_Float16*)bufA + (size_t)NNODES * 128;

  aggregate_half_kernel<<<NNODES / 4, 256, 0, stream>>>((const f16x2*)ybuf, aggx, 1, offs, csr,
                                                        dinv, nullptr);
  gemm_f16_kernel<<<dim3(gridRows, 2), 256, 0, stream>>>(
      aggx, 128, nullptr, 0, nullptr, 0, wt3, 128, 256, bg1, nullptr, g1, 0, 1, NNODES);
  // xw2 = (fp16)((g1 @ Wg2) * dinv[row])  (pre-scale for agg2 folded into epilogue)
  gemm_f16_kernel<<<dim3(gridRows, 1), 256, 0, stream>>>(
      g1, 256, nullptr, 0, nullptr, 0, wt4, 256, 128, nullptr, dinv, xw2, 0, 1, NNODES);
  aggregate_half_kernel<<<NNODES / 4, 256, 0, stream>>>((const f16x2*)xw2, g2, 1, offs, csr,
                                                        dinv, bg2);
  gemm_f16_kernel<<<dim3(gridRows, 1), 256, 0, stream>>>(
      xn16, 128, g1, 256, g2, 128, wt5, 512, 128, b_out, nullptr,
      out + (size_t)NNODES * 128, 0, 0, NNODES);
}